// Round 12
// baseline (186.498 us; speedup 1.0000x reference)
//
#include <hip/hip_runtime.h>
#include <math.h>

#define NN   128
#define SS   129          // LDS row stride in float2 (ODD -> conflict-free lane stride)
#define TT   512          // PROVEN: TT=512 no-spill; TT=1024 ALWAYS spills. Never 1024.
#define NPIX 16384        // 128*128
#define EPT  32           // NPIX / TT
#define SG   65           // 64-grid row stride (float2 or float4 units)
#define SG32 33           // 32-grid row stride

// R12 lesson: NO __threadfence() tail / in-kernel MLP fold (cost ~115 us).
// R14: (j1=0,j2=1) on OFF-CENTER 64x64 frequency windows. Proven absmax 0.0.
// R16: j1=1 retired from the 128-grid (off-center 64-window; V = uh/4).
// R17: all j2=3 pairs on the 32-grid (pass32x4; scales per ladder).
// R18: j2=2 pairs on off-center 32-windows (combo). Proven absmax 0.0.
// R19/R20: pre split + occupancy fix; j1=2 fully on 32-grids. absmax 0.0.
// R21 FAILED: gather staging in big = uncoalesced psi at 1 block/CU.
// R23: (0,2)+(0,3) moved to small via global H. NET NEUTRAL (R10): kernels
//      serialize, total = sum; work moved but efficiency matched.
// R24/R25: DUAL-FIELD j1=1 -- two l1 fields per block (G2A/G2B, 66.6 KB),
//      each 64-grid phase does A then B between ONE barrier pair (proven
//      multi-grid pattern from big's 4-grid j2=1). Halves j1=1's barrier
//      count; ihat reads shared. Combos sequential, reusing combo LDS.
//      (R11 bench was an infra failure -- resubmitted unchanged after audit:
//      LDS bounds, ws layout, grid map, reg indexing, Q coverage all OK.)

__device__ __forceinline__ float2 cmul(float2 a, float2 w) {
    return make_float2(a.x * w.x - a.y * w.y, a.x * w.y + a.y * w.x);
}
__device__ __forceinline__ float2 cmulc(float2 a, float2 w) {   // a * conj(w)
    return make_float2(a.x * w.x + a.y * w.y, a.y * w.x - a.x * w.y);
}

// ---------- register FFT codelets (fft4/fft8/fft16 verified R2-R20) ----------
template<int SGN>
__device__ __forceinline__ void fft4(float2* f) {
    float2 t0 = make_float2(f[0].x + f[2].x, f[0].y + f[2].y);
    float2 t1 = make_float2(f[0].x - f[2].x, f[0].y - f[2].y);
    float2 t2 = make_float2(f[1].x + f[3].x, f[1].y + f[3].y);
    float2 t3 = make_float2(f[1].x - f[3].x, f[1].y - f[3].y);
    float2 t3i = (SGN > 0) ? make_float2(-t3.y, t3.x) : make_float2(t3.y, -t3.x);
    f[0] = make_float2(t0.x + t2.x, t0.y + t2.y);
    f[1] = make_float2(t1.x + t3i.x, t1.y + t3i.y);
    f[2] = make_float2(t0.x - t2.x, t0.y - t2.y);
    f[3] = make_float2(t1.x - t3i.x, t1.y - t3i.y);
}

template<int SGN>
__device__ __forceinline__ void fft8(float2* f) {
    const float R = 0.70710678118654752f;
    const float WC[4] = {1.f, R, 0.f, -R};
    const float WS[4] = {0.f, R, 1.f, R};
    #pragma unroll
    for (int stage = 0; stage < 3; ++stage) {
        const int L = 8 >> stage, half = L >> 1, step = 1 << stage;
        #pragma unroll
        for (int base = 0; base < 8; base += L) {
            #pragma unroll
            for (int j = 0; j < half; ++j) {
                float2 u = f[base + j], v = f[base + half + j];
                f[base + j] = make_float2(u.x + v.x, u.y + v.y);
                float dx = u.x - v.x, dy = u.y - v.y;
                const int t = j * step;
                const float wr = WC[t];
                const float wi = (SGN > 0) ? WS[t] : -WS[t];
                f[base + half + j] = make_float2(dx * wr - dy * wi, dx * wi + dy * wr);
            }
        }
    }
    float2 tmp;
    tmp = f[1]; f[1] = f[4]; f[4] = tmp;
    tmp = f[3]; f[3] = f[6]; f[6] = tmp;
}

template<int SGN>
__device__ __forceinline__ void fft16(float2* f) {
    const float WC[8] = {1.f, 0.92387953251f, 0.70710678119f, 0.38268343236f,
                         0.f, -0.38268343236f, -0.70710678119f, -0.92387953251f};
    const float WS[8] = {0.f, 0.38268343236f, 0.70710678119f, 0.92387953251f,
                         1.f, 0.92387953251f, 0.70710678119f, 0.38268343236f};
    #pragma unroll
    for (int stage = 0; stage < 4; ++stage) {
        const int L = 16 >> stage, half = L >> 1, step = 1 << stage;
        #pragma unroll
        for (int base = 0; base < 16; base += L) {
            #pragma unroll
            for (int j = 0; j < half; ++j) {
                float2 u = f[base + j], v = f[base + half + j];
                f[base + j] = make_float2(u.x + v.x, u.y + v.y);
                float dx = u.x - v.x, dy = u.y - v.y;
                const int t = j * step;
                const float wr = WC[t];
                const float wi = (SGN > 0) ? WS[t] : -WS[t];
                f[base + half + j] = make_float2(dx * wr - dy * wi, dx * wi + dy * wr);
            }
        }
    }
    float2 tmp;
    tmp = f[1];  f[1]  = f[8];  f[8]  = tmp;
    tmp = f[2];  f[2]  = f[4];  f[4]  = tmp;
    tmp = f[3];  f[3]  = f[12]; f[12] = tmp;
    tmp = f[5];  f[5]  = f[10]; f[10] = tmp;
    tmp = f[7];  f[7]  = f[14]; f[14] = tmp;
    tmp = f[11]; f[11] = f[13]; f[13] = tmp;
}

__device__ __forceinline__ float waveReduceSum(float v) {
    #pragma unroll
    for (int off = 32; off > 0; off >>= 1) v += __shfl_down(v, off, 64);
    return v;
}

__device__ __forceinline__ void buildTw(float2* tw, int tid) {
    if (tid < 128) {
        float s, c;
        __sincosf((float)tid * 0.04908738521234052f, &s, &c);   // 2*pi/128
        tw[tid] = make_float2(c, s);
    }
}

// ======== 32-grid 4-filter inverse pass (R17 proven) ========
__device__ __forceinline__ float pass32x4(float4* __restrict__ P4a,
                                          float4* __restrict__ P4b,
                                          const float2* __restrict__ tw, int tid) {
    __syncthreads();
    {   // col stepA
        float4* P = (tid & 256) ? P4b : P4a;
        int line = tid & 31, a = (tid >> 5) & 7;
        float2 f0[4], f1[4];
        #pragma unroll
        for (int kb = 0; kb < 4; ++kb) {
            float4 v = P[(4 * a + kb) * SG32 + line];
            f0[kb] = make_float2(v.x, v.y); f1[kb] = make_float2(v.z, v.w);
        }
        fft4<1>(f0); fft4<1>(f1);
        #pragma unroll
        for (int t = 0; t < 4; ++t) {
            float2 w = tw[4 * t * a];
            float2 aa = cmul(f0[t], w), d = cmul(f1[t], w);
            P[(4 * a + t) * SG32 + line] = make_float4(aa.x, aa.y, d.x, d.y);
        }
    }
    __syncthreads();
    if (tid < 256) {   // col stepB
        float4* P = (tid & 128) ? P4b : P4a;
        int line = tid & 31, t = (tid >> 5) & 3;
        float2 f0[8], f1[8];
        #pragma unroll
        for (int a = 0; a < 8; ++a) {
            float4 v = P[(4 * a + t) * SG32 + line];
            f0[a] = make_float2(v.x, v.y); f1[a] = make_float2(v.z, v.w);
        }
        fft8<1>(f0); fft8<1>(f1);
        #pragma unroll
        for (int n1 = 0; n1 < 8; ++n1)
            P[(4 * n1 + t) * SG32 + line] =
                make_float4(f0[n1].x, f0[n1].y, f1[n1].x, f1[n1].y);
    }
    __syncthreads();
    {   // row stepA
        float4* P = (tid & 256) ? P4b : P4a;
        int row = tid & 31, a = (tid >> 5) & 7;
        float4* R = P + row * SG32 + 4 * a;
        float2 f0[4], f1[4];
        #pragma unroll
        for (int kb = 0; kb < 4; ++kb) {
            float4 v = R[kb];
            f0[kb] = make_float2(v.x, v.y); f1[kb] = make_float2(v.z, v.w);
        }
        fft4<1>(f0); fft4<1>(f1);
        #pragma unroll
        for (int t = 0; t < 4; ++t) {
            float2 w = tw[4 * t * a];
            float2 aa = cmul(f0[t], w), d = cmul(f1[t], w);
            R[t] = make_float4(aa.x, aa.y, d.x, d.y);
        }
    }
    __syncthreads();
    float a2 = 0.f;
    if (tid < 256) {   // row stepB + mag
        float4* P = (tid & 128) ? P4b : P4a;
        int row = tid & 31, t = (tid >> 5) & 3;
        float4* R = P + row * SG32 + t;
        float2 f0[8], f1[8];
        #pragma unroll
        for (int a = 0; a < 8; ++a) {
            float4 v = R[4 * a];
            f0[a] = make_float2(v.x, v.y); f1[a] = make_float2(v.z, v.w);
        }
        fft8<1>(f0); fft8<1>(f1);
        #pragma unroll
        for (int n1 = 0; n1 < 8; ++n1) {
            a2 += sqrtf(f0[n1].x * f0[n1].x + f0[n1].y * f0[n1].y);
            a2 += sqrtf(f1[n1].x * f1[n1].x + f1[n1].y * f1[n1].y);
        }
    }
    return a2;
}

// ======== R18: fused 8-filter 32-grid pass ========
__device__ __forceinline__ void pass32combo(float2* __restrict__ Q0, float2* __restrict__ Q1,
                                            float2* __restrict__ Q2, float2* __restrict__ Q3,
                                            float4* __restrict__ Pa, float4* __restrict__ Pb,
                                            const float2* __restrict__ tw, int tid,
                                            float& aq, float& ap) {
    __syncthreads();
    {   // col stepA: threads 0-255 {Q0,Q1,Pa}; 256-511 {Q2,Q3,Pb}
        float2* Qx = (tid & 256) ? Q2 : Q0;
        float2* Qy = (tid & 256) ? Q3 : Q1;
        float4* P  = (tid & 256) ? Pb : Pa;
        int line = tid & 31, a = (tid >> 5) & 7;
        float2 q0[4], q1[4], f0[4], f1[4];
        #pragma unroll
        for (int kb = 0; kb < 4; ++kb) {
            int o = (4 * a + kb) * SG32 + line;
            q0[kb] = Qx[o]; q1[kb] = Qy[o];
            float4 v = P[o];
            f0[kb] = make_float2(v.x, v.y); f1[kb] = make_float2(v.z, v.w);
        }
        fft4<1>(q0); fft4<1>(q1); fft4<1>(f0); fft4<1>(f1);
        #pragma unroll
        for (int t = 0; t < 4; ++t) {
            float2 w = tw[4 * t * a];
            int o = (4 * a + t) * SG32 + line;
            Qx[o] = cmul(q0[t], w); Qy[o] = cmul(q1[t], w);
            float2 aa = cmul(f0[t], w), d = cmul(f1[t], w);
            P[o] = make_float4(aa.x, aa.y, d.x, d.y);
        }
    }
    __syncthreads();
    if (tid < 256) {   // col stepB
        float2* Qx = (tid & 128) ? Q2 : Q0;
        float2* Qy = (tid & 128) ? Q3 : Q1;
        float4* P  = (tid & 128) ? Pb : Pa;
        int line = tid & 31, t = (tid >> 5) & 3;
        float2 q0[8], q1[8], f0[8], f1[8];
        #pragma unroll
        for (int a = 0; a < 8; ++a) {
            int o = (4 * a + t) * SG32 + line;
            q0[a] = Qx[o]; q1[a] = Qy[o];
            float4 v = P[o];
            f0[a] = make_float2(v.x, v.y); f1[a] = make_float2(v.z, v.w);
        }
        fft8<1>(q0); fft8<1>(q1); fft8<1>(f0); fft8<1>(f1);
        #pragma unroll
        for (int n1 = 0; n1 < 8; ++n1) {
            int o = (4 * n1 + t) * SG32 + line;
            Qx[o] = q0[n1]; Qy[o] = q1[n1];
            P[o] = make_float4(f0[n1].x, f0[n1].y, f1[n1].x, f1[n1].y);
        }
    }
    __syncthreads();
    {   // row stepA
        float2* Qx = (tid & 256) ? Q2 : Q0;
        float2* Qy = (tid & 256) ? Q3 : Q1;
        float4* P  = (tid & 256) ? Pb : Pa;
        int row = tid & 31, a = (tid >> 5) & 7;
        int base = row * SG32 + 4 * a;
        float2 q0[4], q1[4], f0[4], f1[4];
        #pragma unroll
        for (int kb = 0; kb < 4; ++kb) {
            q0[kb] = Qx[base + kb]; q1[kb] = Qy[base + kb];
            float4 v = P[base + kb];
            f0[kb] = make_float2(v.x, v.y); f1[kb] = make_float2(v.z, v.w);
        }
        fft4<1>(q0); fft4<1>(q1); fft4<1>(f0); fft4<1>(f1);
        #pragma unroll
        for (int t = 0; t < 4; ++t) {
            float2 w = tw[4 * t * a];
            Qx[base + t] = cmul(q0[t], w); Qy[base + t] = cmul(q1[t], w);
            float2 aa = cmul(f0[t], w), d = cmul(f1[t], w);
            P[base + t] = make_float4(aa.x, aa.y, d.x, d.y);
        }
    }
    __syncthreads();
    aq = 0.f; ap = 0.f;
    if (tid < 256) {   // row stepB + mag (split accumulators)
        float2* Qx = (tid & 128) ? Q2 : Q0;
        float2* Qy = (tid & 128) ? Q3 : Q1;
        float4* P  = (tid & 128) ? Pb : Pa;
        int row = tid & 31, t = (tid >> 5) & 3;
        int base = row * SG32 + t;
        float2 q0[8], q1[8], f0[8], f1[8];
        #pragma unroll
        for (int a = 0; a < 8; ++a) {
            int o = base + 4 * a;
            q0[a] = Qx[o]; q1[a] = Qy[o];
            float4 v = P[o];
            f0[a] = make_float2(v.x, v.y); f1[a] = make_float2(v.z, v.w);
        }
        fft8<1>(q0); fft8<1>(q1); fft8<1>(f0); fft8<1>(f1);
        #pragma unroll
        for (int n1 = 0; n1 < 8; ++n1) {
            aq += sqrtf(q0[n1].x * q0[n1].x + q0[n1].y * q0[n1].y);
            aq += sqrtf(q1[n1].x * q1[n1].x + q1[n1].y * q1[n1].y);
            ap += sqrtf(f0[n1].x * f0[n1].x + f0[n1].y * f0[n1].y);
            ap += sqrtf(f1[n1].x * f1[n1].x + f1[n1].y * f1[n1].y);
        }
    }
}

// ======== 128-grid sweep phases (R6-R13 proven, TT=512) ========
template<int ES, int LS>
__device__ __forceinline__ void fwdA(float2* __restrict__ F,
                                     const float2* __restrict__ tw, int tid) {
    #pragma unroll
    for (int i = 0; i < 4; ++i) {
        int u = i * TT + tid;
        int t = u >> 7, x = u & 127;
        float2* M = F + x * LS;
        float2 f[8];
        #pragma unroll
        for (int n1 = 0; n1 < 8; ++n1) f[n1] = M[(t + 16 * n1) * ES];
        fft8<-1>(f);
        #pragma unroll
        for (int ka = 0; ka < 8; ++ka)
            M[(t + 16 * ka) * ES] = cmulc(f[ka], tw[t * ka]);
    }
}

template<int ES, int LS>
__device__ __forceinline__ void fwdB(float2* __restrict__ F, int tid) {
    #pragma unroll
    for (int i = 0; i < 2; ++i) {
        int u = i * TT + tid;
        int ka = u >> 7, x = u & 127;
        float2* M = F + x * LS;
        float2 g[16];
        #pragma unroll
        for (int t = 0; t < 16; ++t) g[t] = M[(16 * ka + t) * ES];
        fft16<-1>(g);
        #pragma unroll
        for (int kb = 0; kb < 16; ++kb) M[(16 * ka + kb) * ES] = g[kb];
    }
}

__device__ __forceinline__ void fwdB_col_capture(const float2* __restrict__ F, int tid,
                                                 float2* __restrict__ uh) {
    #pragma unroll
    for (int i = 0; i < 2; ++i) {
        int u = i * TT + tid;
        int ka = u >> 7, c = u & 127;
        float2 g[16];
        #pragma unroll
        for (int t = 0; t < 16; ++t) g[t] = F[(16 * ka + t) * SS + c];
        fft16<-1>(g);
        #pragma unroll
        for (int kb = 0; kb < 16; ++kb) uh[i * 16 + kb] = g[kb];
    }
}

template<int ES, int LS>
__device__ __forceinline__ void invA(float2* __restrict__ F,
                                     const float2* __restrict__ tw, int tid) {
    #pragma unroll
    for (int i = 0; i < 2; ++i) {
        int u = i * TT + tid;
        int ka = u >> 7, x = u & 127;
        float2* M = F + x * LS;
        float2 g[16];
        #pragma unroll
        for (int kb = 0; kb < 16; ++kb) g[kb] = M[(16 * ka + kb) * ES];
        fft16<1>(g);
        #pragma unroll
        for (int t = 0; t < 16; ++t)
            M[(16 * ka + t) * ES] = cmul(g[t], tw[t * ka]);
    }
}

template<int ES, int LS>
__device__ __forceinline__ void invB(float2* __restrict__ F, int tid) {
    #pragma unroll
    for (int i = 0; i < 4; ++i) {
        int u = i * TT + tid;
        int t = u >> 7, x = u & 127;
        float2* M = F + x * LS;
        float2 f[8];
        #pragma unroll
        for (int ka = 0; ka < 8; ++ka) f[ka] = M[(16 * ka + t) * ES];
        fft8<1>(f);
        #pragma unroll
        for (int nh = 0; nh < 8; ++nh) M[(t + 16 * nh) * ES] = f[nh];
    }
}

// FUSED: inverse row stepB -> |.| (raw, acc) -> forward row stepA (same cells).
__device__ __forceinline__ void invBmag_fwdA_row(float2* __restrict__ F,
                                                 const float2* __restrict__ tw,
                                                 int tid, float& acc) {
    #pragma unroll
    for (int i = 0; i < 4; ++i) {
        int u = i * TT + tid;
        int t = u >> 7, x = u & 127;
        float2* M = F + x * SS;
        float2 f[8];
        #pragma unroll
        for (int ka = 0; ka < 8; ++ka) f[ka] = M[16 * ka + t];
        fft8<1>(f);
        #pragma unroll
        for (int nh = 0; nh < 8; ++nh) {
            float m = sqrtf(f[nh].x * f[nh].x + f[nh].y * f[nh].y);
            acc += m;
            f[nh] = make_float2(m, 0.f);
        }
        fft8<-1>(f);
        #pragma unroll
        for (int ka = 0; ka < 8; ++ka)
            M[t + 16 * ka] = cmulc(f[ka], tw[t * ka]);
    }
}

// ---------- K_pre1 (R19/R20): row-strip FFT along c + filters + zero ----------
__global__ __attribute__((amdgpu_flat_work_group_size(TT, TT), amdgpu_waves_per_eu(4, 4)))
void k_pre1(const float* __restrict__ img,
            float* __restrict__ psi,
            float2* __restrict__ interm,
            float* __restrict__ coeffs) {
    __shared__ __align__(16) float2 F[32 * SS];
    __shared__ float2 tw[128];
    int blk = blockIdx.x, tid = threadIdx.x;
    if (blk >= 256) {
        if (blk == 384) {
            for (int i = tid; i < 64 * 11; i += TT) coeffs[i] = 0.f;
            return;
        }
        int fb = blk - 256;
        int f = fb >> 3, chunk = fb & 7;          // 16 filters x 8 chunks
        int j = f >> 2, l = f & 3;
        float k0    = 2.35619449019234493f / (float)(1 << j);
        float sigma = 0.8f * (float)(1 << j);
        float s2    = sigma * sigma;
        float theta = 0.78539816339744831f * (float)l;
        float k0x = k0 * cosf(theta);
        float k0y = k0 * sinf(theta);
        float beta = expf(-0.5f * s2 * k0 * k0);
        const float FSTEP = 0.04908738521234052f;
        float* dst = psi + (size_t)f * NPIX;
        int i0 = chunk * 2048, i1 = i0 + 2048;
        for (int i = i0 + tid; i < i1; i += TT) {
            int pr = i >> 7, pc = i & 127;
            int kr = (pr >> 4) + 8 * (pr & 15);
            int kc = (pc >> 4) + 8 * (pc & 15);
            float fr = (float)(kr < 64 ? kr : kr - 128) * FSTEP;
            float fc = (float)(kc < 64 ? kc : kc - 128) * FSTEP;
            float dx = fr - k0x, dy = fc - k0y;
            float g1 = expf(-0.5f * s2 * (dx * dx + dy * dy));
            float g0 = expf(-0.5f * s2 * (fr * fr + fc * fc));
            dst[i] = g1 - beta * g0;
        }
        return;
    }
    int b = blk >> 2, q = blk & 3;
    buildTw(tw, tid);
    const float* im = img + (size_t)b * NPIX + (size_t)q * 32 * NN;
    #pragma unroll
    for (int k = 0; k < 8; ++k) {
        int e = k * TT + tid;                      // 0..4095
        F[(e >> 7) * SS + (e & 127)] = make_float2(im[e], 0.f);
    }
    __syncthreads();
    {   // stepA along c (fft8): 32 rows x 16 t = 512
        int x = tid & 31, t = tid >> 5;
        float2* M = F + x * SS;
        float2 f[8];
        #pragma unroll
        for (int n1 = 0; n1 < 8; ++n1) f[n1] = M[t + 16 * n1];
        fft8<-1>(f);
        #pragma unroll
        for (int ka = 0; ka < 8; ++ka)
            M[t + 16 * ka] = cmulc(f[ka], tw[t * ka]);
    }
    __syncthreads();
    if (tid < 256) {   // stepB along c (fft16): 32 rows x 8 ka
        int x = tid & 31, ka = tid >> 5;
        float2* M = F + x * SS + 16 * ka;
        float2 g[16];
        #pragma unroll
        for (int t = 0; t < 16; ++t) g[t] = M[t];
        fft16<-1>(g);
        #pragma unroll
        for (int kb = 0; kb < 16; ++kb) M[kb] = g[kb];
    }
    __syncthreads();
    float2* dst = interm + (size_t)b * NPIX + (size_t)q * 32 * NN;
    #pragma unroll
    for (int k = 0; k < 8; ++k) {
        int e = k * TT + tid;
        dst[e] = F[(e >> 7) * SS + (e & 127)];
    }
}

// ---------- K_pre2 (R19/R20): col-strip FFT along r + capture + s0 ----------
__global__ __attribute__((amdgpu_flat_work_group_size(TT, TT), amdgpu_waves_per_eu(4, 4)))
void k_pre2(float2* __restrict__ ihat,
            float* __restrict__ coeffs) {
    __shared__ __align__(16) float2 F[128 * 33];
    __shared__ float2 tw[128];
    int blk = blockIdx.x, tid = threadIdx.x;
    int b = blk >> 2, q = blk & 3;
    buildTw(tw, tid);
    float2* base = ihat + (size_t)b * NPIX + q * 32;
    #pragma unroll
    for (int k = 0; k < 8; ++k) {
        int e = k * TT + tid;                      // 0..4095
        int r = e >> 5, cl = e & 31;
        F[r * 33 + cl] = base[r * NN + cl];
    }
    __syncthreads();
    {   // stepA along r (fft8): 32 cols x 16 t = 512
        int cl = tid & 31, t = tid >> 5;
        float2 f[8];
        #pragma unroll
        for (int n1 = 0; n1 < 8; ++n1) f[n1] = F[(t + 16 * n1) * 33 + cl];
        fft8<-1>(f);
        #pragma unroll
        for (int ka = 0; ka < 8; ++ka)
            F[(t + 16 * ka) * 33 + cl] = cmulc(f[ka], tw[t * ka]);
    }
    __syncthreads();
    if (tid < 256) {   // stepB along r (fft16) + store + s0
        int cl = tid & 31, ka = tid >> 5;
        float2 g[16];
        #pragma unroll
        for (int t = 0; t < 16; ++t) g[t] = F[(16 * ka + t) * 33 + cl];
        fft16<-1>(g);
        float2* dst = base + cl;
        #pragma unroll
        for (int kb = 0; kb < 16; ++kb)
            dst[(16 * ka + kb) * NN] = g[kb];
        if (q == 0 && cl == 0 && ka == 0)
            coeffs[b * 11 + 0] = g[0].x * (1.f / 16384.f);
    }
}

// ---------- K_scat_big (R23): j1=0 first order + j2=1 + H write ----------
__global__ __attribute__((amdgpu_flat_work_group_size(TT, TT), amdgpu_waves_per_eu(2, 2)))
void k_scat_big(const float2* __restrict__ ihat,
                const float* __restrict__ psi,
                float* __restrict__ coeffs,
                float2* __restrict__ Hg) {
    __shared__ __align__(16) float2 F[16640];
    __shared__ float2 tw[128];
    float2* G2a = F;
    float2* G2b = F + 4160;
    float2* G2c = F + 8320;
    float2* G2d = F + 12480;
    int tid = threadIdx.x;
    int x = blockIdx.x;
    int b = x & 63, l1 = x >> 6;                       // j1 == 0
    const float2* ih = ihat + (size_t)b * NPIX;
    const float*  p1 = psi + (size_t)l1 * NPIX;
    buildTw(tw, tid);

    const float S1_128 = 9.3132257461547852e-10f;   // 2^-30
    const float S2TR   = 5.6843418860808015e-14f;   // 2^-44

    int kalo = tid >> 7, c = tid & 127;
    {
        #pragma unroll
        for (int i = 0; i < 2; ++i) {
            int ka = kalo + 4 * i;
            float2 g[16];
            #pragma unroll
            for (int kb = 0; kb < 16; ++kb) {
                int e = (16 * ka + kb) * NN + c;
                float2 z = ih[e];
                float  p = p1[e];
                g[kb] = make_float2(z.x * p, z.y * p);
            }
            fft16<1>(g);
            #pragma unroll
            for (int t = 0; t < 16; ++t)
                F[(16 * ka + t) * SS + c] = cmul(g[t], tw[t * ka]);
        }
    }
    __syncthreads();
    invB<SS, 1>(F, tid);      __syncthreads();
    invA<1, SS>(F, tw, tid);  __syncthreads();
    float acc = 0.f;
    invBmag_fwdA_row(F, tw, tid, acc);
    float ws1 = waveReduceSum(acc);
    if ((tid & 63) == 0) atomicAdd(&coeffs[b * 11 + 1], ws1 * S1_128);
    __syncthreads();
    fwdB<1, SS>(F, tid);      __syncthreads();
    fwdA<SS, 1>(F, tw, tid);  __syncthreads();
    float2 uh[32];
    fwdB_col_capture(F, tid, uh);
    __syncthreads();   // capture done -> F reusable (grids alias it)

    int m = c & 15;
    bool colKeep = (m < 4) || (m >= 12);
    int pc64 = 8 * (c >> 4) + ((m < 4) ? m : (m - 8));
    int fc = (c >> 4) + 8 * (c & 15);

    // ===== R23: H write to GLOBAL (central +-32 of uh; R13-proven scatter) =====
    {
        float2* Hf = Hg + ((size_t)(b * 4 + l1)) * 4096;
        if (colKeep) {
            #pragma unroll
            for (int i = 0; i < 2; ++i) {
                int ka = kalo + 4 * i;
                #pragma unroll
                for (int kb = 0; kb < 16; ++kb) {
                    if (kb < 4 || kb >= 12) {
                        int pr64 = 8 * ka + ((kb < 4) ? kb : (kb - 8));
                        Hf[pr64 * 64 + pc64] = uh[i * 16 + kb];
                    }
                }
            }
        }
    }

    {
        // ===== (j1=0, j2=1): ONE pass, 4 off-center 64-windows (R14 mapping) =====
        const int ORW[4] = {21, 15, 0, -15};
        const int OCW[4] = { 0, 15, 21,  15};
        bool ckw[4]; int pcw[4];
        #pragma unroll
        for (int w = 0; w < 4; ++w) {
            int dc = (fc - OCW[w]) & 127;
            ckw[w] = (dc < 32) || (dc >= 96);
            int uc = (dc < 32) ? dc : (dc - 64);
            pcw[w] = 8 * (uc & 7) + (uc >> 3);
        }
        #pragma unroll
        for (int i = 0; i < 2; ++i) {
            int ka = kalo + 4 * i;
            #pragma unroll
            for (int kb = 0; kb < 16; ++kb) {
                int fr = ka + 8 * kb;
                float2 z = uh[i * 16 + kb];
                int e = (16 * ka + kb) * NN + c;
                #pragma unroll
                for (int w = 0; w < 4; ++w) {
                    if (ckw[w]) {
                        int dr = (fr - ORW[w]) & 127;
                        if (dr < 32 || dr >= 96) {
                            int ur = (dr < 32) ? dr : (dr - 64);
                            int pr = 8 * (ur & 7) + (ur >> 3);
                            float pv = psi[(size_t)(4 + w) * NPIX + e];
                            float2* G = (w == 0) ? G2a : (w == 1) ? G2b
                                       : (w == 2) ? G2c : G2d;
                            G[pr * SG + pcw[w]] = make_float2(z.x * pv, z.y * pv);
                        }
                    }
                }
            }
        }
        __syncthreads();
        {   // col stepA (4 grids, full width)
            int col = tid & 63, k8 = tid >> 6;
            float2 f0[8], f1[8], f2[8], f3[8];
            #pragma unroll
            for (int kb = 0; kb < 8; ++kb) {
                int o = (8 * k8 + kb) * SG + col;
                f0[kb] = G2a[o]; f1[kb] = G2b[o]; f2[kb] = G2c[o]; f3[kb] = G2d[o];
            }
            fft8<1>(f0); fft8<1>(f1); fft8<1>(f2); fft8<1>(f3);
            #pragma unroll
            for (int q = 0; q < 8; ++q) {
                float2 w = tw[2 * q * k8];
                int o = (8 * k8 + q) * SG + col;
                G2a[o] = cmul(f0[q], w); G2b[o] = cmul(f1[q], w);
                G2c[o] = cmul(f2[q], w); G2d[o] = cmul(f3[q], w);
            }
        }
        __syncthreads();
        {   // col stepB
            int col = tid & 63, q = tid >> 6;
            float2 f0[8], f1[8], f2[8], f3[8];
            #pragma unroll
            for (int k8 = 0; k8 < 8; ++k8) {
                int o = (8 * k8 + q) * SG + col;
                f0[k8] = G2a[o]; f1[k8] = G2b[o]; f2[k8] = G2c[o]; f3[k8] = G2d[o];
            }
            fft8<1>(f0); fft8<1>(f1); fft8<1>(f2); fft8<1>(f3);
            #pragma unroll
            for (int n1 = 0; n1 < 8; ++n1) {
                int o = (8 * n1 + q) * SG + col;
                G2a[o] = f0[n1]; G2b[o] = f1[n1]; G2c[o] = f2[n1]; G2d[o] = f3[n1];
            }
        }
        __syncthreads();
        {   // row stepA
            int row = tid & 63, k8 = tid >> 6;
            int base = row * SG + 8 * k8;
            float2 f0[8], f1[8], f2[8], f3[8];
            #pragma unroll
            for (int kb = 0; kb < 8; ++kb) {
                f0[kb] = G2a[base + kb]; f1[kb] = G2b[base + kb];
                f2[kb] = G2c[base + kb]; f3[kb] = G2d[base + kb];
            }
            fft8<1>(f0); fft8<1>(f1); fft8<1>(f2); fft8<1>(f3);
            #pragma unroll
            for (int q = 0; q < 8; ++q) {
                float2 w = tw[2 * q * k8];
                G2a[base + q] = cmul(f0[q], w); G2b[base + q] = cmul(f1[q], w);
                G2c[base + q] = cmul(f2[q], w); G2d[base + q] = cmul(f3[q], w);
            }
        }
        __syncthreads();
        float a2 = 0.f;
        {   // row stepB + mag (all 4 -> same coeff)
            int row = tid & 63, q = tid >> 6;
            int base = row * SG + q;
            float2 f0[8], f1[8], f2[8], f3[8];
            #pragma unroll
            for (int k8 = 0; k8 < 8; ++k8) {
                int o = base + 8 * k8;
                f0[k8] = G2a[o]; f1[k8] = G2b[o]; f2[k8] = G2c[o]; f3[k8] = G2d[o];
            }
            fft8<1>(f0); fft8<1>(f1); fft8<1>(f2); fft8<1>(f3);
            #pragma unroll
            for (int n1 = 0; n1 < 8; ++n1) {
                a2 += sqrtf(f0[n1].x * f0[n1].x + f0[n1].y * f0[n1].y);
                a2 += sqrtf(f1[n1].x * f1[n1].x + f1[n1].y * f1[n1].y);
                a2 += sqrtf(f2[n1].x * f2[n1].x + f2[n1].y * f2[n1].y);
                a2 += sqrtf(f3[n1].x * f3[n1].x + f3[n1].y * f3[n1].y);
            }
        }
        float ws2 = waveReduceSum(a2);
        if ((tid & 63) == 0) atomicAdd(&coeffs[b * 11 + 5 + 0], ws2 * S2TR);
    }
}

// ---------- K_scat_small (R24): dual j1=1 + combo03 + j1=2 + j1=3 ----------
// grid 896: [0,128) j1=1 dual; [128,384) combo03; [384,640) j1=2; [640,896) j1=3
__global__ __attribute__((amdgpu_flat_work_group_size(TT, TT), amdgpu_waves_per_eu(4, 4)))
void k_scat_small(const float2* __restrict__ ihat,
                  const float* __restrict__ psi,
                  float* __restrict__ coeffs,
                  const float2* __restrict__ Hg) {
    __shared__ __align__(16) float2 S[8448];
    __shared__ float2 tw[128];
    float2* G32 = S;
    float2* Qs0 = S;
    float2* Qs1 = S + 1056;
    float2* Qs2 = S + 2112;
    float2* Qs3 = S + 3168;
    float4* Psa = (float4*)(S + 4224);
    float4* Psb = (float4*)(S + 6336);
    int tid = threadIdx.x;
    int x = blockIdx.x;
    buildTw(tw, tid);

    const float S1_64 = 3.7252902984619141e-9f;    // 2^-28
    const float S1_32 = 1.4901161193847656e-8f;    // 2^-26
    const float S2_32 = 9.0949470177292824e-13f;   // 2^-40 (32-grid from V64)

    int kalo = tid >> 7, c = tid & 127;

    if (x < 128) {
        // ===== R24: j1=1 DUAL-FIELD (two l1 per block) on off-center 64-window =====
        int b = x & 63, ph = x >> 6;
        int l1a = 2 * ph, l1b = 2 * ph + 1;
        const float2* ih = ihat + (size_t)b * NPIX;
        const float* p1a = psi + (size_t)(4 + l1a) * NPIX;
        const float* p1b = psi + (size_t)(4 + l1b) * NPIX;
        float2* G2A = S;
        float2* G2B = S + 4160;
        const int OR1[4] = {21, 15, 0, -15};
        const int OC1[4] = { 0, 15, 21,  15};
        int fc = (c >> 4) + 8 * (c & 15);
        int dcA = (fc - OC1[l1a]) & 127;
        bool ckA = (dcA < 32) || (dcA >= 96);
        int ucwA = (dcA < 32) ? dcA : (dcA - 64);
        int pcdA = 8 * (ucwA & 7) + (ucwA >> 3);
        int dcB = (fc - OC1[l1b]) & 127;
        bool ckB = (dcB < 32) || (dcB >= 96);
        int ucwB = (dcB < 32) ? dcB : (dcB - 64);
        int pcdB = 8 * (ucwB & 7) + (ucwB >> 3);
        #pragma unroll
        for (int i = 0; i < 2; ++i) {
            int ka = kalo + 4 * i;
            #pragma unroll
            for (int kb = 0; kb < 16; ++kb) {
                int fr = ka + 8 * kb;
                int e = (16 * ka + kb) * NN + c;
                float2 z = ih[e];
                if (ckA) {
                    int dr = (fr - OR1[l1a]) & 127;
                    if (dr < 32 || dr >= 96) {
                        int ur = (dr < 32) ? dr : (dr - 64);
                        int pr = 8 * (ur & 7) + (ur >> 3);
                        float p = p1a[e];
                        G2A[pr * SG + pcdA] = make_float2(z.x * p, z.y * p);
                    }
                }
                if (ckB) {
                    int dr = (fr - OR1[l1b]) & 127;
                    if (dr < 32 || dr >= 96) {
                        int ur = (dr < 32) ? dr : (dr - 64);
                        int pr = 8 * (ur & 7) + (ur >> 3);
                        float p = p1b[e];
                        G2B[pr * SG + pcdB] = make_float2(z.x * p, z.y * p);
                    }
                }
            }
        }
        __syncthreads();
        {   // col stepA (inverse) dual
            int col = tid & 63, k8 = tid >> 6;
            {
                float2 f[8];
                #pragma unroll
                for (int kb = 0; kb < 8; ++kb) f[kb] = G2A[(8 * k8 + kb) * SG + col];
                fft8<1>(f);
                #pragma unroll
                for (int q = 0; q < 8; ++q)
                    G2A[(8 * k8 + q) * SG + col] = cmul(f[q], tw[2 * q * k8]);
            }
            {
                float2 f[8];
                #pragma unroll
                for (int kb = 0; kb < 8; ++kb) f[kb] = G2B[(8 * k8 + kb) * SG + col];
                fft8<1>(f);
                #pragma unroll
                for (int q = 0; q < 8; ++q)
                    G2B[(8 * k8 + q) * SG + col] = cmul(f[q], tw[2 * q * k8]);
            }
        }
        __syncthreads();
        {   // col stepB dual
            int col = tid & 63, q = tid >> 6;
            {
                float2 f[8];
                #pragma unroll
                for (int k8 = 0; k8 < 8; ++k8) f[k8] = G2A[(8 * k8 + q) * SG + col];
                fft8<1>(f);
                #pragma unroll
                for (int n1 = 0; n1 < 8; ++n1) G2A[(8 * n1 + q) * SG + col] = f[n1];
            }
            {
                float2 f[8];
                #pragma unroll
                for (int k8 = 0; k8 < 8; ++k8) f[k8] = G2B[(8 * k8 + q) * SG + col];
                fft8<1>(f);
                #pragma unroll
                for (int n1 = 0; n1 < 8; ++n1) G2B[(8 * n1 + q) * SG + col] = f[n1];
            }
        }
        __syncthreads();
        {   // row stepA (inverse) dual
            int row = tid & 63, k8 = tid >> 6;
            {
                float2* R = G2A + row * SG + 8 * k8;
                float2 f[8];
                #pragma unroll
                for (int kb = 0; kb < 8; ++kb) f[kb] = R[kb];
                fft8<1>(f);
                #pragma unroll
                for (int q = 0; q < 8; ++q) R[q] = cmul(f[q], tw[2 * q * k8]);
            }
            {
                float2* R = G2B + row * SG + 8 * k8;
                float2 f[8];
                #pragma unroll
                for (int kb = 0; kb < 8; ++kb) f[kb] = R[kb];
                fft8<1>(f);
                #pragma unroll
                for (int q = 0; q < 8; ++q) R[q] = cmul(f[q], tw[2 * q * k8]);
            }
        }
        __syncthreads();
        float acc = 0.f;
        {   // FUSED64 dual: rowB inv -> |.| -> rowA fwd (both fields, acc shared)
            int row = tid & 63, q = tid >> 6;
            {
                float2* R = G2A + row * SG + q;
                float2 f[8];
                #pragma unroll
                for (int k8 = 0; k8 < 8; ++k8) f[k8] = R[8 * k8];
                fft8<1>(f);
                #pragma unroll
                for (int n1 = 0; n1 < 8; ++n1) {
                    float mg = sqrtf(f[n1].x * f[n1].x + f[n1].y * f[n1].y);
                    acc += mg;
                    f[n1] = make_float2(mg, 0.f);
                }
                fft8<-1>(f);
                #pragma unroll
                for (int ka = 0; ka < 8; ++ka)
                    R[8 * ka] = cmulc(f[ka], tw[2 * q * ka]);
            }
            {
                float2* R = G2B + row * SG + q;
                float2 f[8];
                #pragma unroll
                for (int k8 = 0; k8 < 8; ++k8) f[k8] = R[8 * k8];
                fft8<1>(f);
                #pragma unroll
                for (int n1 = 0; n1 < 8; ++n1) {
                    float mg = sqrtf(f[n1].x * f[n1].x + f[n1].y * f[n1].y);
                    acc += mg;
                    f[n1] = make_float2(mg, 0.f);
                }
                fft8<-1>(f);
                #pragma unroll
                for (int ka = 0; ka < 8; ++ka)
                    R[8 * ka] = cmulc(f[ka], tw[2 * q * ka]);
            }
        }
        float ws1 = waveReduceSum(acc);
        if ((tid & 63) == 0) atomicAdd(&coeffs[b * 11 + 2], ws1 * S1_64);
        __syncthreads();
        {   // row stepB (forward) dual
            int row2 = tid & 63, ka = tid >> 6;
            {
                float2* R2 = G2A + row2 * SG + 8 * ka;
                float2 g[8];
                #pragma unroll
                for (int t = 0; t < 8; ++t) g[t] = R2[t];
                fft8<-1>(g);
                #pragma unroll
                for (int kb = 0; kb < 8; ++kb) R2[kb] = g[kb];
            }
            {
                float2* R2 = G2B + row2 * SG + 8 * ka;
                float2 g[8];
                #pragma unroll
                for (int t = 0; t < 8; ++t) g[t] = R2[t];
                fft8<-1>(g);
                #pragma unroll
                for (int kb = 0; kb < 8; ++kb) R2[kb] = g[kb];
            }
        }
        __syncthreads();
        {   // col stepA (forward) dual
            int col = tid & 63, t = tid >> 6;
            {
                float2 g[8];
                #pragma unroll
                for (int n1 = 0; n1 < 8; ++n1) g[n1] = G2A[(t + 8 * n1) * SG + col];
                fft8<-1>(g);
                #pragma unroll
                for (int ka = 0; ka < 8; ++ka)
                    G2A[(t + 8 * ka) * SG + col] = cmulc(g[ka], tw[2 * t * ka]);
            }
            {
                float2 g[8];
                #pragma unroll
                for (int n1 = 0; n1 < 8; ++n1) g[n1] = G2B[(t + 8 * n1) * SG + col];
                fft8<-1>(g);
                #pragma unroll
                for (int ka = 0; ka < 8; ++ka)
                    G2B[(t + 8 * ka) * SG + col] = cmulc(g[ka], tw[2 * t * ka]);
            }
        }
        __syncthreads();
        float2 vhA[8], vhB[8];
        int c6 = tid & 63, ka8 = tid >> 6;
        {   // col stepB (forward) dual -> V captured to registers
            {
                float2 g[8];
                #pragma unroll
                for (int t = 0; t < 8; ++t) g[t] = G2A[(8 * ka8 + t) * SG + c6];
                fft8<-1>(g);
                #pragma unroll
                for (int kb = 0; kb < 8; ++kb) vhA[kb] = g[kb];
            }
            {
                float2 g[8];
                #pragma unroll
                for (int t = 0; t < 8; ++t) g[t] = G2B[(8 * ka8 + t) * SG + c6];
                fft8<-1>(g);
                #pragma unroll
                for (int kb = 0; kb < 8; ++kb) vhB[kb] = g[kb];
            }
        }
        __syncthreads();   // G2A/G2B dead -> combo grids (aliases) safe

        // shared combo geometry (field-independent)
        int uc64 = 8 * (c6 & 7) + (c6 >> 3);
        int fc128 = (uc64 < 32) ? uc64 : (uc64 + 64);
        int scI = 16 * (fc128 & 7) + (fc128 >> 3);
        int se[8];
        #pragma unroll
        for (int kb = 0; kb < 8; ++kb) {
            int ur = 8 * kb + ka8;
            int fr128 = (ur < 32) ? ur : (ur + 64);
            se[kb] = (16 * (fr128 & 7) + (fr128 >> 3)) * NN + scI;
        }
        const int OR2[4] = {9, 6, 0, -6};
        const int OC2[4] = {0, 6, 9,  6};
        bool ckq[4]; int pcq[4];
        #pragma unroll
        for (int w = 0; w < 4; ++w) {
            int dcw = (uc64 - OC2[w]) & 63;
            ckq[w] = (dcw < 16) || (dcw >= 48);
            int f32c = (dcw < 16) ? dcw : (dcw - 32);
            pcq[w] = 4 * (f32c & 7) + (f32c >> 3);
        }
        int m6 = c6 & 7;
        bool ckV = (m6 < 2) || (m6 >= 6);
        int p32c = 4 * (c6 >> 3) + ((m6 < 2) ? m6 : (m6 - 4));
        const float* p30 = psi + (size_t)12 * NPIX;

        #pragma unroll
        for (int fld = 0; fld < 2; ++fld) {
            const float2* vh = (fld == 0) ? vhA : vhB;
            #pragma unroll
            for (int kb = 0; kb < 8; ++kb) {
                int ur = 8 * kb + ka8;
                float2 z = vh[kb];
                int e = se[kb];
                #pragma unroll
                for (int w = 0; w < 4; ++w) {
                    if (ckq[w]) {
                        int dr = (ur - OR2[w]) & 63;
                        if (dr < 16 || dr >= 48) {
                            int f32r = (dr < 16) ? dr : (dr - 32);
                            int pr = 4 * (f32r & 7) + (f32r >> 3);
                            float pv = psi[(size_t)(8 + w) * NPIX + e];
                            float2* Q = (w == 0) ? Qs0 : (w == 1) ? Qs1
                                       : (w == 2) ? Qs2 : Qs3;
                            Q[pr * SG32 + pcq[w]] = make_float2(z.x * pv, z.y * pv);
                        }
                    }
                }
                if (ckV && (kb < 2 || kb >= 6)) {
                    int pr32 = 4 * ka8 + (kb & 3);
                    float a0 = p30[e], a1 = p30[NPIX + e];
                    float a2f = p30[2 * NPIX + e], a3 = p30[3 * NPIX + e];
                    Psa[pr32 * SG32 + p32c] =
                        make_float4(z.x * a0, z.y * a0, z.x * a1, z.y * a1);
                    Psb[pr32 * SG32 + p32c] =
                        make_float4(z.x * a2f, z.y * a2f, z.x * a3, z.y * a3);
                }
            }
            float aq, ap;
            pass32combo(Qs0, Qs1, Qs2, Qs3, Psa, Psb, tw, tid, aq, ap);
            float wsq = waveReduceSum(aq);
            float wsp = waveReduceSum(ap);
            if ((tid & 63) == 0) {
                atomicAdd(&coeffs[b * 11 + 5 + 3], wsq * S2_32);
                atomicAdd(&coeffs[b * 11 + 5 + 4], wsp * S2_32);
            }
            __syncthreads();   // combo LDS reuse between fields
        }
        return;
    }

    if (x < 384) {
        // ===== R23 combo03: (0,2)+(0,3) from global H, proven 32-grid combo =====
        int y = x - 128;
        int b = y & 63, l1 = y >> 6;
        const float S2_03 = 2.2737367544323206e-13f;   // 2^-42
        const float2* Hf = Hg + ((size_t)(b * 4 + l1)) * 4096;
        int m = c & 15;
        bool colKeep = (m < 4) || (m >= 12);
        int pc64 = 8 * (c >> 4) + ((m < 4) ? m : (m - 8));
        int fc = (c >> 4) + 8 * (c & 15);
        const int OR2[4] = {9, 6, 0, -6};
        const int OC2[4] = {0, 6, 9,  6};
        bool ckq[4]; int pcq[4];
        #pragma unroll
        for (int w = 0; w < 4; ++w) {
            int dc = (fc - OC2[w]) & 127;
            ckq[w] = (dc < 16) || (dc >= 112);
            int f32c = (dc < 16) ? dc : (dc - 96);
            pcq[w] = 4 * (f32c & 7) + (f32c >> 3);
        }
        bool ck32 = (m < 2) || (m >= 14);
        int pc32 = 4 * (c >> 4) + ((m < 2) ? m : (m - 12));
        const float* p20 = psi + (size_t)8 * NPIX;
        const float* p30 = psi + (size_t)12 * NPIX;
        if (colKeep) {
            #pragma unroll
            for (int i = 0; i < 2; ++i) {
                int ka = kalo + 4 * i;
                #pragma unroll
                for (int kb = 0; kb < 16; ++kb) {
                    if (kb < 4 || kb >= 12) {
                        int pr64 = 8 * ka + ((kb < 4) ? kb : (kb - 8));
                        float2 z = Hf[pr64 * 64 + pc64];
                        int fr = ka + 8 * kb;
                        int e = (16 * ka + kb) * NN + c;
                        #pragma unroll
                        for (int w = 0; w < 4; ++w) {
                            if (ckq[w]) {
                                int dr = (fr - OR2[w]) & 127;
                                if (dr < 16 || dr >= 112) {
                                    int f32r = (dr < 16) ? dr : (dr - 96);
                                    int pr = 4 * (f32r & 7) + (f32r >> 3);
                                    float pv = p20[(size_t)w * NPIX + e];
                                    float2* Q = (w == 0) ? Qs0 : (w == 1) ? Qs1
                                               : (w == 2) ? Qs2 : Qs3;
                                    Q[pr * SG32 + pcq[w]] = make_float2(z.x * pv, z.y * pv);
                                }
                            }
                        }
                        if (ck32 && (kb < 2 || kb >= 14)) {
                            int pr32 = 4 * ka + ((kb < 2) ? kb : (kb - 12));
                            float a0 = p30[e], a1 = p30[NPIX + e];
                            float a2f = p30[2 * NPIX + e], a3 = p30[3 * NPIX + e];
                            Psa[pr32 * SG32 + pc32] =
                                make_float4(z.x * a0, z.y * a0, z.x * a1, z.y * a1);
                            Psb[pr32 * SG32 + pc32] =
                                make_float4(z.x * a2f, z.y * a2f, z.x * a3, z.y * a3);
                        }
                    }
                }
            }
        }
        float aq, ap;
        pass32combo(Qs0, Qs1, Qs2, Qs3, Psa, Psb, tw, tid, aq, ap);
        float wsq = waveReduceSum(aq);
        float wsp = waveReduceSum(ap);
        if ((tid & 63) == 0) {
            atomicAdd(&coeffs[b * 11 + 5 + 1], wsq * S2_03);
            atomicAdd(&coeffs[b * 11 + 5 + 2], wsp * S2_03);
        }
        return;
    }

    if (x < 640) {
        // ===== j1 == 2 (R20): ENTIRE branch on off-center 32-windows =====
        int y = x - 384;
        int b = y & 63, l1 = y >> 6;
        const float2* ih = ihat + (size_t)b * NPIX;
        const float* p1 = psi + (size_t)(8 + l1) * NPIX;
        const float S2_23 = 3.6379788070917130e-12f;   // 2^-38
        const int OR1[4] = {9, 6, 0, -6};
        const int OC1[4] = {0, 6, 9,  6};
        float2* G = S;                                  // 32x33 float2
        float4* Pa = (float4*)(S + 1088);               // S[1088..3200)
        float4* Pb = (float4*)(S + 3200);               // S[3200..5312)
        int fc = (c >> 4) + 8 * (c & 15);
        int dc = (fc - OC1[l1]) & 127;
        bool ck = (dc < 16) || (dc >= 112);
        int f32c = (dc < 16) ? dc : (dc - 96);
        int pcd = 4 * (f32c & 7) + (f32c >> 3);
        if (ck) {
            #pragma unroll
            for (int i = 0; i < 2; ++i) {
                int ka = kalo + 4 * i;
                #pragma unroll
                for (int kb = 0; kb < 16; ++kb) {
                    int fr = ka + 8 * kb;
                    int dr = (fr - OR1[l1]) & 127;
                    if (dr < 16 || dr >= 112) {
                        int f32r = (dr < 16) ? dr : (dr - 96);
                        int pr = 4 * (f32r & 7) + (f32r >> 3);
                        int e = (16 * ka + kb) * NN + c;
                        float2 z = ih[e];
                        float  p = p1[e];
                        G[pr * SG32 + pcd] = make_float2(z.x * p, z.y * p);
                    }
                }
            }
        }
        __syncthreads();
        if (tid < 256) {   // col stepA (inverse)
            int line = tid & 31, a = tid >> 5;
            float2 f[4];
            #pragma unroll
            for (int kb = 0; kb < 4; ++kb) f[kb] = G[(4 * a + kb) * SG32 + line];
            fft4<1>(f);
            #pragma unroll
            for (int t = 0; t < 4; ++t)
                G[(4 * a + t) * SG32 + line] = cmul(f[t], tw[4 * t * a]);
        }
        __syncthreads();
        if (tid < 128) {   // col stepB (inverse)
            int line = tid & 31, t = tid >> 5;
            float2 f[8];
            #pragma unroll
            for (int a = 0; a < 8; ++a) f[a] = G[(4 * a + t) * SG32 + line];
            fft8<1>(f);
            #pragma unroll
            for (int n1 = 0; n1 < 8; ++n1) G[(4 * n1 + t) * SG32 + line] = f[n1];
        }
        __syncthreads();
        if (tid < 256) {   // row stepA (inverse)
            int row = tid & 31, a = tid >> 5;
            float2* R = G + row * SG32 + 4 * a;
            float2 f[4];
            #pragma unroll
            for (int kb = 0; kb < 4; ++kb) f[kb] = R[kb];
            fft4<1>(f);
            #pragma unroll
            for (int t = 0; t < 4; ++t) R[t] = cmul(f[t], tw[4 * t * a]);
        }
        __syncthreads();
        float acc = 0.f;
        if (tid < 128) {   // row stepB (inverse) + mag + writeback (m,0)
            int row = tid & 31, t = tid >> 5;
            float2* R = G + row * SG32 + t;
            float2 f[8];
            #pragma unroll
            for (int a = 0; a < 8; ++a) f[a] = R[4 * a];
            fft8<1>(f);
            #pragma unroll
            for (int n1 = 0; n1 < 8; ++n1) {
                float mg = sqrtf(f[n1].x * f[n1].x + f[n1].y * f[n1].y);
                acc += mg;
                R[4 * n1] = make_float2(mg, 0.f);
            }
        }
        float ws1 = waveReduceSum(acc);
        if ((tid & 63) == 0 && tid < 128) atomicAdd(&coeffs[b * 11 + 3], ws1 * S1_32);
        __syncthreads();
        if (tid < 256) {   // row stepA (forward)
            int row = tid & 31, a = tid >> 5;
            float2* R = G + row * SG32 + 4 * a;
            float2 f[4];
            #pragma unroll
            for (int kb = 0; kb < 4; ++kb) f[kb] = R[kb];
            fft4<-1>(f);
            #pragma unroll
            for (int t = 0; t < 4; ++t) R[t] = cmulc(f[t], tw[4 * t * a]);
        }
        __syncthreads();
        if (tid < 128) {   // row stepB (forward)
            int row = tid & 31, t = tid >> 5;
            float2* R = G + row * SG32 + t;
            float2 f[8];
            #pragma unroll
            for (int a = 0; a < 8; ++a) f[a] = R[4 * a];
            fft8<-1>(f);
            #pragma unroll
            for (int n1 = 0; n1 < 8; ++n1) R[4 * n1] = f[n1];
        }
        __syncthreads();
        if (tid < 256) {   // col stepA (forward)
            int line = tid & 31, a = tid >> 5;
            float2 f[4];
            #pragma unroll
            for (int kb = 0; kb < 4; ++kb) f[kb] = G[(4 * a + kb) * SG32 + line];
            fft4<-1>(f);
            #pragma unroll
            for (int t = 0; t < 4; ++t)
                G[(4 * a + t) * SG32 + line] = cmulc(f[t], tw[4 * t * a]);
        }
        __syncthreads();
        if (tid < 128) {   // col stepB (forward) -> V32 in G (perm layout)
            int line = tid & 31, t = tid >> 5;
            float2 f[8];
            #pragma unroll
            for (int a = 0; a < 8; ++a) f[a] = G[(4 * a + t) * SG32 + line];
            fft8<-1>(f);
            #pragma unroll
            for (int n1 = 0; n1 < 8; ++n1) G[(4 * n1 + t) * SG32 + line] = f[n1];
        }
        __syncthreads();
        {   // (2,3) staging: dest slot == V32 slot (same perm); psi at slot freq
            const float* q0 = psi + (size_t)12 * NPIX;
            const float* q1 = q0 + NPIX;
            const float* q2 = q1 + NPIX;
            const float* q3 = q2 + NPIX;
            #pragma unroll
            for (int ii = 0; ii < 2; ++ii) {
                int s = ii * 512 + tid;
                int pr = s >> 5, pc = s & 31;
                int ur = (pr >> 2) + 8 * (pr & 3);
                int uc = (pc >> 2) + 8 * (pc & 3);
                int fr = (ur < 16) ? ur : (ur + 96);
                int fcc = (uc < 16) ? uc : (uc + 96);
                int e = (16 * (fr & 7) + (fr >> 3)) * NN
                      + 16 * (fcc & 7) + (fcc >> 3);
                float2 z = G[pr * SG32 + pc];
                float a0 = q0[e], a1 = q1[e], a2f = q2[e], a3 = q3[e];
                Pa[pr * SG32 + pc] = make_float4(z.x * a0, z.y * a0, z.x * a1, z.y * a1);
                Pb[pr * SG32 + pc] = make_float4(z.x * a2f, z.y * a2f, z.x * a3, z.y * a3);
            }
        }
        float a2 = pass32x4(Pa, Pb, tw, tid);
        float ws2 = waveReduceSum(a2);
        if ((tid & 63) == 0) atomicAdd(&coeffs[b * 11 + 5 + 5], ws2 * S2_23);
        return;
    }

    {   // ===== j1=3: 32-grid first order (psi_{j1=3} support +-16) =====
        int y = x - 640;
        int b = y & 63, l1 = y >> 6;
        const float2* ih = ihat + (size_t)b * NPIX;
        const float* p1 = psi + (size_t)(12 + l1) * NPIX;
        int m = c & 15;
        bool ck32 = (m < 2) || (m >= 14);
        int pc32 = 4 * (c >> 4) + ((m < 2) ? m : (m - 12));
        if (ck32) {
            #pragma unroll
            for (int i = 0; i < 2; ++i) {
                int ka = kalo + 4 * i;
                #pragma unroll
                for (int kb = 0; kb < 16; ++kb) {
                    if (kb < 2 || kb >= 14) {
                        int e = (16 * ka + kb) * NN + c;
                        float2 z = ih[e];
                        float  p = p1[e];
                        int pr32 = 4 * ka + ((kb < 2) ? kb : (kb - 12));
                        G32[pr32 * SG32 + pc32] = make_float2(z.x * p, z.y * p);
                    }
                }
            }
        }
        __syncthreads();
        if (tid < 256) {   // col stepA: fft4 over b per a (32 lines x 8 a)
            int line = tid & 31, a = tid >> 5;
            float2 f[4];
            #pragma unroll
            for (int kb = 0; kb < 4; ++kb) f[kb] = G32[(4 * a + kb) * SG32 + line];
            fft4<1>(f);
            #pragma unroll
            for (int t = 0; t < 4; ++t)
                G32[(4 * a + t) * SG32 + line] = cmul(f[t], tw[4 * t * a]);
        }
        __syncthreads();
        if (tid < 128) {   // col stepB: fft8 over a per t (32 lines x 4 t)
            int line = tid & 31, t = tid >> 5;
            float2 f[8];
            #pragma unroll
            for (int a = 0; a < 8; ++a) f[a] = G32[(4 * a + t) * SG32 + line];
            fft8<1>(f);
            #pragma unroll
            for (int n1 = 0; n1 < 8; ++n1) G32[(4 * n1 + t) * SG32 + line] = f[n1];
        }
        __syncthreads();
        if (tid < 256) {   // row stepA
            int row = tid & 31, a = tid >> 5;
            float2* R = G32 + row * SG32 + 4 * a;
            float2 f[4];
            #pragma unroll
            for (int kb = 0; kb < 4; ++kb) f[kb] = R[kb];
            fft4<1>(f);
            #pragma unroll
            for (int t = 0; t < 4; ++t) R[t] = cmul(f[t], tw[4 * t * a]);
        }
        __syncthreads();
        float acc = 0.f;
        if (tid < 128) {   // row stepB + mag
            int row = tid & 31, t = tid >> 5;
            float2* R = G32 + row * SG32 + t;
            float2 f[8];
            #pragma unroll
            for (int a = 0; a < 8; ++a) f[a] = R[4 * a];
            fft8<1>(f);
            #pragma unroll
            for (int n1 = 0; n1 < 8; ++n1)
                acc += sqrtf(f[n1].x * f[n1].x + f[n1].y * f[n1].y);
        }
        float ws1 = waveReduceSum(acc);
        if ((tid & 63) == 0 && tid < 128) atomicAdd(&coeffs[b * 11 + 4], ws1 * S1_32);
    }
}

// ---------- K_mlp: tiny MLP head (separate launch -- R12 lesson) ----------
__global__ void k_mlp(const float* __restrict__ coeffs,
                      const float* __restrict__ w1, const float* __restrict__ b1,
                      const float* __restrict__ w2, const float* __restrict__ b2,
                      float* __restrict__ out) {
    int b = threadIdx.x;
    if (b >= 64) return;
    float c[11];
    #pragma unroll
    for (int i = 0; i < 11; ++i) c[i] = coeffs[b * 11 + i];
    float h[4];
    #pragma unroll
    for (int k = 0; k < 4; ++k) {
        float s = b1[k];
        #pragma unroll
        for (int i = 0; i < 11; ++i) s += w1[k * 11 + i] * c[i];
        h[k] = fmaxf(s, 0.f);
    }
    #pragma unroll
    for (int o = 0; o < 10; ++o) {
        float s = b2[o];
        #pragma unroll
        for (int k = 0; k < 4; ++k) s += w2[o * 4 + k] * h[k];
        out[b * 10 + o] = 1.f / (1.f + expf(-s));
    }
}

extern "C" void kernel_launch(void* const* d_in, const int* in_sizes, int n_in,
                              void* d_out, int out_size, void* d_ws, size_t ws_size,
                              hipStream_t stream) {
    const float* img = (const float*)d_in[0];
    const float* w1  = (const float*)d_in[1];
    const float* b1  = (const float*)d_in[2];
    const float* w2  = (const float*)d_in[3];
    const float* b2  = (const float*)d_in[4];
    float* out = (float*)d_out;

    float*  ws     = (float*)d_ws;
    float*  psi    = ws;                                   // 16*NPIX floats
    float2* ihat   = (float2*)(ws + 16 * NPIX);            // 64*NPIX float2
    float2* Hg     = ihat + (size_t)64 * NPIX;             // 256*4096 float2 (R23)
    float*  coeffs = ws + 16 * NPIX + 2 * 64 * NPIX + 2 * 256 * 4096;

    hipLaunchKernelGGL(k_pre1,       dim3(385), dim3(TT), 0, stream, img, psi, ihat, coeffs);
    hipLaunchKernelGGL(k_pre2,       dim3(256), dim3(TT), 0, stream, ihat, coeffs);
    hipLaunchKernelGGL(k_scat_big,   dim3(256), dim3(TT), 0, stream, ihat, psi, coeffs, Hg);
    hipLaunchKernelGGL(k_scat_small, dim3(896), dim3(TT), 0, stream, ihat, psi, coeffs, Hg);
    hipLaunchKernelGGL(k_mlp,        dim3(1),   dim3(64), 0, stream, coeffs, w1, b1, w2, b2, out);
}

// Round 13
// 167.712 us; speedup vs baseline: 1.1120x; 1.1120x over previous
//
#include <hip/hip_runtime.h>
#include <math.h>

#define NN   128
#define SS   129          // LDS row stride in float2 (ODD -> conflict-free lane stride)
#define TT   512          // PROVEN: TT=512 no-spill; TT=1024 ALWAYS spills. Never 1024.
#define NPIX 16384        // 128*128
#define EPT  32           // NPIX / TT
#define SG   65           // 64-grid row stride (float2 or float4 units)
#define SG32 33           // 32-grid row stride

// R12 lesson: NO __threadfence() tail / in-kernel MLP fold (cost ~115 us).
// R14: (j1=0,j2=1) on OFF-CENTER 64x64 frequency windows. Proven absmax 0.0.
// R16: j1=1 retired from the 128-grid (off-center 64-window; V = uh/4).
// R17: all j2=3 pairs on the 32-grid (pass32x4; scales per ladder).
// R18: j2=2 pairs on off-center 32-windows (combo). Proven absmax 0.0.
// R19/R20: pre split + occupancy fix; j1=2 fully on 32-grids. absmax 0.0.
// R21 FAILED: gather staging in big = uncoalesced psi at 1 block/CU.
// R23: (0,2)+(0,3) moved to small via global H (net neutral but keeps big light).
// R24 FAILED (R12 bench): dual-field j1=1 -> VGPR capped at 64 + scratch spill
//      (VALUBusy 26%, small 63-92us). LESSON: per-thread state budget in small
//      is ~full; no dual-field. REVERTED to R10-measured form (168.2us).

__device__ __forceinline__ float2 cmul(float2 a, float2 w) {
    return make_float2(a.x * w.x - a.y * w.y, a.x * w.y + a.y * w.x);
}
__device__ __forceinline__ float2 cmulc(float2 a, float2 w) {   // a * conj(w)
    return make_float2(a.x * w.x + a.y * w.y, a.y * w.x - a.x * w.y);
}

// ---------- register FFT codelets (fft4/fft8/fft16 verified R2-R20) ----------
template<int SGN>
__device__ __forceinline__ void fft4(float2* f) {
    float2 t0 = make_float2(f[0].x + f[2].x, f[0].y + f[2].y);
    float2 t1 = make_float2(f[0].x - f[2].x, f[0].y - f[2].y);
    float2 t2 = make_float2(f[1].x + f[3].x, f[1].y + f[3].y);
    float2 t3 = make_float2(f[1].x - f[3].x, f[1].y - f[3].y);
    float2 t3i = (SGN > 0) ? make_float2(-t3.y, t3.x) : make_float2(t3.y, -t3.x);
    f[0] = make_float2(t0.x + t2.x, t0.y + t2.y);
    f[1] = make_float2(t1.x + t3i.x, t1.y + t3i.y);
    f[2] = make_float2(t0.x - t2.x, t0.y - t2.y);
    f[3] = make_float2(t1.x - t3i.x, t1.y - t3i.y);
}

template<int SGN>
__device__ __forceinline__ void fft8(float2* f) {
    const float R = 0.70710678118654752f;
    const float WC[4] = {1.f, R, 0.f, -R};
    const float WS[4] = {0.f, R, 1.f, R};
    #pragma unroll
    for (int stage = 0; stage < 3; ++stage) {
        const int L = 8 >> stage, half = L >> 1, step = 1 << stage;
        #pragma unroll
        for (int base = 0; base < 8; base += L) {
            #pragma unroll
            for (int j = 0; j < half; ++j) {
                float2 u = f[base + j], v = f[base + half + j];
                f[base + j] = make_float2(u.x + v.x, u.y + v.y);
                float dx = u.x - v.x, dy = u.y - v.y;
                const int t = j * step;
                const float wr = WC[t];
                const float wi = (SGN > 0) ? WS[t] : -WS[t];
                f[base + half + j] = make_float2(dx * wr - dy * wi, dx * wi + dy * wr);
            }
        }
    }
    float2 tmp;
    tmp = f[1]; f[1] = f[4]; f[4] = tmp;
    tmp = f[3]; f[3] = f[6]; f[6] = tmp;
}

template<int SGN>
__device__ __forceinline__ void fft16(float2* f) {
    const float WC[8] = {1.f, 0.92387953251f, 0.70710678119f, 0.38268343236f,
                         0.f, -0.38268343236f, -0.70710678119f, -0.92387953251f};
    const float WS[8] = {0.f, 0.38268343236f, 0.70710678119f, 0.92387953251f,
                         1.f, 0.92387953251f, 0.70710678119f, 0.38268343236f};
    #pragma unroll
    for (int stage = 0; stage < 4; ++stage) {
        const int L = 16 >> stage, half = L >> 1, step = 1 << stage;
        #pragma unroll
        for (int base = 0; base < 16; base += L) {
            #pragma unroll
            for (int j = 0; j < half; ++j) {
                float2 u = f[base + j], v = f[base + half + j];
                f[base + j] = make_float2(u.x + v.x, u.y + v.y);
                float dx = u.x - v.x, dy = u.y - v.y;
                const int t = j * step;
                const float wr = WC[t];
                const float wi = (SGN > 0) ? WS[t] : -WS[t];
                f[base + half + j] = make_float2(dx * wr - dy * wi, dx * wi + dy * wr);
            }
        }
    }
    float2 tmp;
    tmp = f[1];  f[1]  = f[8];  f[8]  = tmp;
    tmp = f[2];  f[2]  = f[4];  f[4]  = tmp;
    tmp = f[3];  f[3]  = f[12]; f[12] = tmp;
    tmp = f[5];  f[5]  = f[10]; f[10] = tmp;
    tmp = f[7];  f[7]  = f[14]; f[14] = tmp;
    tmp = f[11]; f[11] = f[13]; f[13] = tmp;
}

__device__ __forceinline__ float waveReduceSum(float v) {
    #pragma unroll
    for (int off = 32; off > 0; off >>= 1) v += __shfl_down(v, off, 64);
    return v;
}

__device__ __forceinline__ void buildTw(float2* tw, int tid) {
    if (tid < 128) {
        float s, c;
        __sincosf((float)tid * 0.04908738521234052f, &s, &c);   // 2*pi/128
        tw[tid] = make_float2(c, s);
    }
}

// ======== 32-grid 4-filter inverse pass (R17 proven) ========
__device__ __forceinline__ float pass32x4(float4* __restrict__ P4a,
                                          float4* __restrict__ P4b,
                                          const float2* __restrict__ tw, int tid) {
    __syncthreads();
    {   // col stepA
        float4* P = (tid & 256) ? P4b : P4a;
        int line = tid & 31, a = (tid >> 5) & 7;
        float2 f0[4], f1[4];
        #pragma unroll
        for (int kb = 0; kb < 4; ++kb) {
            float4 v = P[(4 * a + kb) * SG32 + line];
            f0[kb] = make_float2(v.x, v.y); f1[kb] = make_float2(v.z, v.w);
        }
        fft4<1>(f0); fft4<1>(f1);
        #pragma unroll
        for (int t = 0; t < 4; ++t) {
            float2 w = tw[4 * t * a];
            float2 aa = cmul(f0[t], w), d = cmul(f1[t], w);
            P[(4 * a + t) * SG32 + line] = make_float4(aa.x, aa.y, d.x, d.y);
        }
    }
    __syncthreads();
    if (tid < 256) {   // col stepB
        float4* P = (tid & 128) ? P4b : P4a;
        int line = tid & 31, t = (tid >> 5) & 3;
        float2 f0[8], f1[8];
        #pragma unroll
        for (int a = 0; a < 8; ++a) {
            float4 v = P[(4 * a + t) * SG32 + line];
            f0[a] = make_float2(v.x, v.y); f1[a] = make_float2(v.z, v.w);
        }
        fft8<1>(f0); fft8<1>(f1);
        #pragma unroll
        for (int n1 = 0; n1 < 8; ++n1)
            P[(4 * n1 + t) * SG32 + line] =
                make_float4(f0[n1].x, f0[n1].y, f1[n1].x, f1[n1].y);
    }
    __syncthreads();
    {   // row stepA
        float4* P = (tid & 256) ? P4b : P4a;
        int row = tid & 31, a = (tid >> 5) & 7;
        float4* R = P + row * SG32 + 4 * a;
        float2 f0[4], f1[4];
        #pragma unroll
        for (int kb = 0; kb < 4; ++kb) {
            float4 v = R[kb];
            f0[kb] = make_float2(v.x, v.y); f1[kb] = make_float2(v.z, v.w);
        }
        fft4<1>(f0); fft4<1>(f1);
        #pragma unroll
        for (int t = 0; t < 4; ++t) {
            float2 w = tw[4 * t * a];
            float2 aa = cmul(f0[t], w), d = cmul(f1[t], w);
            R[t] = make_float4(aa.x, aa.y, d.x, d.y);
        }
    }
    __syncthreads();
    float a2 = 0.f;
    if (tid < 256) {   // row stepB + mag
        float4* P = (tid & 128) ? P4b : P4a;
        int row = tid & 31, t = (tid >> 5) & 3;
        float4* R = P + row * SG32 + t;
        float2 f0[8], f1[8];
        #pragma unroll
        for (int a = 0; a < 8; ++a) {
            float4 v = R[4 * a];
            f0[a] = make_float2(v.x, v.y); f1[a] = make_float2(v.z, v.w);
        }
        fft8<1>(f0); fft8<1>(f1);
        #pragma unroll
        for (int n1 = 0; n1 < 8; ++n1) {
            a2 += sqrtf(f0[n1].x * f0[n1].x + f0[n1].y * f0[n1].y);
            a2 += sqrtf(f1[n1].x * f1[n1].x + f1[n1].y * f1[n1].y);
        }
    }
    return a2;
}

// ======== R18: fused 8-filter 32-grid pass ========
__device__ __forceinline__ void pass32combo(float2* __restrict__ Q0, float2* __restrict__ Q1,
                                            float2* __restrict__ Q2, float2* __restrict__ Q3,
                                            float4* __restrict__ Pa, float4* __restrict__ Pb,
                                            const float2* __restrict__ tw, int tid,
                                            float& aq, float& ap) {
    __syncthreads();
    {   // col stepA: threads 0-255 {Q0,Q1,Pa}; 256-511 {Q2,Q3,Pb}
        float2* Qx = (tid & 256) ? Q2 : Q0;
        float2* Qy = (tid & 256) ? Q3 : Q1;
        float4* P  = (tid & 256) ? Pb : Pa;
        int line = tid & 31, a = (tid >> 5) & 7;
        float2 q0[4], q1[4], f0[4], f1[4];
        #pragma unroll
        for (int kb = 0; kb < 4; ++kb) {
            int o = (4 * a + kb) * SG32 + line;
            q0[kb] = Qx[o]; q1[kb] = Qy[o];
            float4 v = P[o];
            f0[kb] = make_float2(v.x, v.y); f1[kb] = make_float2(v.z, v.w);
        }
        fft4<1>(q0); fft4<1>(q1); fft4<1>(f0); fft4<1>(f1);
        #pragma unroll
        for (int t = 0; t < 4; ++t) {
            float2 w = tw[4 * t * a];
            int o = (4 * a + t) * SG32 + line;
            Qx[o] = cmul(q0[t], w); Qy[o] = cmul(q1[t], w);
            float2 aa = cmul(f0[t], w), d = cmul(f1[t], w);
            P[o] = make_float4(aa.x, aa.y, d.x, d.y);
        }
    }
    __syncthreads();
    if (tid < 256) {   // col stepB
        float2* Qx = (tid & 128) ? Q2 : Q0;
        float2* Qy = (tid & 128) ? Q3 : Q1;
        float4* P  = (tid & 128) ? Pb : Pa;
        int line = tid & 31, t = (tid >> 5) & 3;
        float2 q0[8], q1[8], f0[8], f1[8];
        #pragma unroll
        for (int a = 0; a < 8; ++a) {
            int o = (4 * a + t) * SG32 + line;
            q0[a] = Qx[o]; q1[a] = Qy[o];
            float4 v = P[o];
            f0[a] = make_float2(v.x, v.y); f1[a] = make_float2(v.z, v.w);
        }
        fft8<1>(q0); fft8<1>(q1); fft8<1>(f0); fft8<1>(f1);
        #pragma unroll
        for (int n1 = 0; n1 < 8; ++n1) {
            int o = (4 * n1 + t) * SG32 + line;
            Qx[o] = q0[n1]; Qy[o] = q1[n1];
            P[o] = make_float4(f0[n1].x, f0[n1].y, f1[n1].x, f1[n1].y);
        }
    }
    __syncthreads();
    {   // row stepA
        float2* Qx = (tid & 256) ? Q2 : Q0;
        float2* Qy = (tid & 256) ? Q3 : Q1;
        float4* P  = (tid & 256) ? Pb : Pa;
        int row = tid & 31, a = (tid >> 5) & 7;
        int base = row * SG32 + 4 * a;
        float2 q0[4], q1[4], f0[4], f1[4];
        #pragma unroll
        for (int kb = 0; kb < 4; ++kb) {
            q0[kb] = Qx[base + kb]; q1[kb] = Qy[base + kb];
            float4 v = P[base + kb];
            f0[kb] = make_float2(v.x, v.y); f1[kb] = make_float2(v.z, v.w);
        }
        fft4<1>(q0); fft4<1>(q1); fft4<1>(f0); fft4<1>(f1);
        #pragma unroll
        for (int t = 0; t < 4; ++t) {
            float2 w = tw[4 * t * a];
            Qx[base + t] = cmul(q0[t], w); Qy[base + t] = cmul(q1[t], w);
            float2 aa = cmul(f0[t], w), d = cmul(f1[t], w);
            P[base + t] = make_float4(aa.x, aa.y, d.x, d.y);
        }
    }
    __syncthreads();
    aq = 0.f; ap = 0.f;
    if (tid < 256) {   // row stepB + mag (split accumulators)
        float2* Qx = (tid & 128) ? Q2 : Q0;
        float2* Qy = (tid & 128) ? Q3 : Q1;
        float4* P  = (tid & 128) ? Pb : Pa;
        int row = tid & 31, t = (tid >> 5) & 3;
        int base = row * SG32 + t;
        float2 q0[8], q1[8], f0[8], f1[8];
        #pragma unroll
        for (int a = 0; a < 8; ++a) {
            int o = base + 4 * a;
            q0[a] = Qx[o]; q1[a] = Qy[o];
            float4 v = P[o];
            f0[a] = make_float2(v.x, v.y); f1[a] = make_float2(v.z, v.w);
        }
        fft8<1>(q0); fft8<1>(q1); fft8<1>(f0); fft8<1>(f1);
        #pragma unroll
        for (int n1 = 0; n1 < 8; ++n1) {
            aq += sqrtf(q0[n1].x * q0[n1].x + q0[n1].y * q0[n1].y);
            aq += sqrtf(q1[n1].x * q1[n1].x + q1[n1].y * q1[n1].y);
            ap += sqrtf(f0[n1].x * f0[n1].x + f0[n1].y * f0[n1].y);
            ap += sqrtf(f1[n1].x * f1[n1].x + f1[n1].y * f1[n1].y);
        }
    }
}

// ======== 128-grid sweep phases (R6-R13 proven, TT=512) ========
template<int ES, int LS>
__device__ __forceinline__ void fwdA(float2* __restrict__ F,
                                     const float2* __restrict__ tw, int tid) {
    #pragma unroll
    for (int i = 0; i < 4; ++i) {
        int u = i * TT + tid;
        int t = u >> 7, x = u & 127;
        float2* M = F + x * LS;
        float2 f[8];
        #pragma unroll
        for (int n1 = 0; n1 < 8; ++n1) f[n1] = M[(t + 16 * n1) * ES];
        fft8<-1>(f);
        #pragma unroll
        for (int ka = 0; ka < 8; ++ka)
            M[(t + 16 * ka) * ES] = cmulc(f[ka], tw[t * ka]);
    }
}

template<int ES, int LS>
__device__ __forceinline__ void fwdB(float2* __restrict__ F, int tid) {
    #pragma unroll
    for (int i = 0; i < 2; ++i) {
        int u = i * TT + tid;
        int ka = u >> 7, x = u & 127;
        float2* M = F + x * LS;
        float2 g[16];
        #pragma unroll
        for (int t = 0; t < 16; ++t) g[t] = M[(16 * ka + t) * ES];
        fft16<-1>(g);
        #pragma unroll
        for (int kb = 0; kb < 16; ++kb) M[(16 * ka + kb) * ES] = g[kb];
    }
}

__device__ __forceinline__ void fwdB_col_capture(const float2* __restrict__ F, int tid,
                                                 float2* __restrict__ uh) {
    #pragma unroll
    for (int i = 0; i < 2; ++i) {
        int u = i * TT + tid;
        int ka = u >> 7, c = u & 127;
        float2 g[16];
        #pragma unroll
        for (int t = 0; t < 16; ++t) g[t] = F[(16 * ka + t) * SS + c];
        fft16<-1>(g);
        #pragma unroll
        for (int kb = 0; kb < 16; ++kb) uh[i * 16 + kb] = g[kb];
    }
}

template<int ES, int LS>
__device__ __forceinline__ void invA(float2* __restrict__ F,
                                     const float2* __restrict__ tw, int tid) {
    #pragma unroll
    for (int i = 0; i < 2; ++i) {
        int u = i * TT + tid;
        int ka = u >> 7, x = u & 127;
        float2* M = F + x * LS;
        float2 g[16];
        #pragma unroll
        for (int kb = 0; kb < 16; ++kb) g[kb] = M[(16 * ka + kb) * ES];
        fft16<1>(g);
        #pragma unroll
        for (int t = 0; t < 16; ++t)
            M[(16 * ka + t) * ES] = cmul(g[t], tw[t * ka]);
    }
}

template<int ES, int LS>
__device__ __forceinline__ void invB(float2* __restrict__ F, int tid) {
    #pragma unroll
    for (int i = 0; i < 4; ++i) {
        int u = i * TT + tid;
        int t = u >> 7, x = u & 127;
        float2* M = F + x * LS;
        float2 f[8];
        #pragma unroll
        for (int ka = 0; ka < 8; ++ka) f[ka] = M[(16 * ka + t) * ES];
        fft8<1>(f);
        #pragma unroll
        for (int nh = 0; nh < 8; ++nh) M[(t + 16 * nh) * ES] = f[nh];
    }
}

// FUSED: inverse row stepB -> |.| (raw, acc) -> forward row stepA (same cells).
__device__ __forceinline__ void invBmag_fwdA_row(float2* __restrict__ F,
                                                 const float2* __restrict__ tw,
                                                 int tid, float& acc) {
    #pragma unroll
    for (int i = 0; i < 4; ++i) {
        int u = i * TT + tid;
        int t = u >> 7, x = u & 127;
        float2* M = F + x * SS;
        float2 f[8];
        #pragma unroll
        for (int ka = 0; ka < 8; ++ka) f[ka] = M[16 * ka + t];
        fft8<1>(f);
        #pragma unroll
        for (int nh = 0; nh < 8; ++nh) {
            float m = sqrtf(f[nh].x * f[nh].x + f[nh].y * f[nh].y);
            acc += m;
            f[nh] = make_float2(m, 0.f);
        }
        fft8<-1>(f);
        #pragma unroll
        for (int ka = 0; ka < 8; ++ka)
            M[t + 16 * ka] = cmulc(f[ka], tw[t * ka]);
    }
}

// ---------- K_pre1 (R19/R20): row-strip FFT along c + filters + zero ----------
__global__ __attribute__((amdgpu_flat_work_group_size(TT, TT), amdgpu_waves_per_eu(4, 4)))
void k_pre1(const float* __restrict__ img,
            float* __restrict__ psi,
            float2* __restrict__ interm,
            float* __restrict__ coeffs) {
    __shared__ __align__(16) float2 F[32 * SS];
    __shared__ float2 tw[128];
    int blk = blockIdx.x, tid = threadIdx.x;
    if (blk >= 256) {
        if (blk == 384) {
            for (int i = tid; i < 64 * 11; i += TT) coeffs[i] = 0.f;
            return;
        }
        int fb = blk - 256;
        int f = fb >> 3, chunk = fb & 7;          // 16 filters x 8 chunks
        int j = f >> 2, l = f & 3;
        float k0    = 2.35619449019234493f / (float)(1 << j);
        float sigma = 0.8f * (float)(1 << j);
        float s2    = sigma * sigma;
        float theta = 0.78539816339744831f * (float)l;
        float k0x = k0 * cosf(theta);
        float k0y = k0 * sinf(theta);
        float beta = expf(-0.5f * s2 * k0 * k0);
        const float FSTEP = 0.04908738521234052f;
        float* dst = psi + (size_t)f * NPIX;
        int i0 = chunk * 2048, i1 = i0 + 2048;
        for (int i = i0 + tid; i < i1; i += TT) {
            int pr = i >> 7, pc = i & 127;
            int kr = (pr >> 4) + 8 * (pr & 15);
            int kc = (pc >> 4) + 8 * (pc & 15);
            float fr = (float)(kr < 64 ? kr : kr - 128) * FSTEP;
            float fc = (float)(kc < 64 ? kc : kc - 128) * FSTEP;
            float dx = fr - k0x, dy = fc - k0y;
            float g1 = expf(-0.5f * s2 * (dx * dx + dy * dy));
            float g0 = expf(-0.5f * s2 * (fr * fr + fc * fc));
            dst[i] = g1 - beta * g0;
        }
        return;
    }
    int b = blk >> 2, q = blk & 3;
    buildTw(tw, tid);
    const float* im = img + (size_t)b * NPIX + (size_t)q * 32 * NN;
    #pragma unroll
    for (int k = 0; k < 8; ++k) {
        int e = k * TT + tid;                      // 0..4095
        F[(e >> 7) * SS + (e & 127)] = make_float2(im[e], 0.f);
    }
    __syncthreads();
    {   // stepA along c (fft8): 32 rows x 16 t = 512
        int x = tid & 31, t = tid >> 5;
        float2* M = F + x * SS;
        float2 f[8];
        #pragma unroll
        for (int n1 = 0; n1 < 8; ++n1) f[n1] = M[t + 16 * n1];
        fft8<-1>(f);
        #pragma unroll
        for (int ka = 0; ka < 8; ++ka)
            M[t + 16 * ka] = cmulc(f[ka], tw[t * ka]);
    }
    __syncthreads();
    if (tid < 256) {   // stepB along c (fft16): 32 rows x 8 ka
        int x = tid & 31, ka = tid >> 5;
        float2* M = F + x * SS + 16 * ka;
        float2 g[16];
        #pragma unroll
        for (int t = 0; t < 16; ++t) g[t] = M[t];
        fft16<-1>(g);
        #pragma unroll
        for (int kb = 0; kb < 16; ++kb) M[kb] = g[kb];
    }
    __syncthreads();
    float2* dst = interm + (size_t)b * NPIX + (size_t)q * 32 * NN;
    #pragma unroll
    for (int k = 0; k < 8; ++k) {
        int e = k * TT + tid;
        dst[e] = F[(e >> 7) * SS + (e & 127)];
    }
}

// ---------- K_pre2 (R19/R20): col-strip FFT along r + capture + s0 ----------
__global__ __attribute__((amdgpu_flat_work_group_size(TT, TT), amdgpu_waves_per_eu(4, 4)))
void k_pre2(float2* __restrict__ ihat,
            float* __restrict__ coeffs) {
    __shared__ __align__(16) float2 F[128 * 33];
    __shared__ float2 tw[128];
    int blk = blockIdx.x, tid = threadIdx.x;
    int b = blk >> 2, q = blk & 3;
    buildTw(tw, tid);
    float2* base = ihat + (size_t)b * NPIX + q * 32;
    #pragma unroll
    for (int k = 0; k < 8; ++k) {
        int e = k * TT + tid;                      // 0..4095
        int r = e >> 5, cl = e & 31;
        F[r * 33 + cl] = base[r * NN + cl];
    }
    __syncthreads();
    {   // stepA along r (fft8): 32 cols x 16 t = 512
        int cl = tid & 31, t = tid >> 5;
        float2 f[8];
        #pragma unroll
        for (int n1 = 0; n1 < 8; ++n1) f[n1] = F[(t + 16 * n1) * 33 + cl];
        fft8<-1>(f);
        #pragma unroll
        for (int ka = 0; ka < 8; ++ka)
            F[(t + 16 * ka) * 33 + cl] = cmulc(f[ka], tw[t * ka]);
    }
    __syncthreads();
    if (tid < 256) {   // stepB along r (fft16) + store + s0
        int cl = tid & 31, ka = tid >> 5;
        float2 g[16];
        #pragma unroll
        for (int t = 0; t < 16; ++t) g[t] = F[(16 * ka + t) * 33 + cl];
        fft16<-1>(g);
        float2* dst = base + cl;
        #pragma unroll
        for (int kb = 0; kb < 16; ++kb)
            dst[(16 * ka + kb) * NN] = g[kb];
        if (q == 0 && cl == 0 && ka == 0)
            coeffs[b * 11 + 0] = g[0].x * (1.f / 16384.f);
    }
}

// ---------- K_scat_big (R23): j1=0 first order + j2=1 + H write ----------
__global__ __attribute__((amdgpu_flat_work_group_size(TT, TT), amdgpu_waves_per_eu(2, 2)))
void k_scat_big(const float2* __restrict__ ihat,
                const float* __restrict__ psi,
                float* __restrict__ coeffs,
                float2* __restrict__ Hg) {
    // F: 16640 float2 = 133,120 B.
    //   128-grid phases: F[0..16512) stride SS.
    //   j2=1 one-pass: G2a..G2d = F + {0,4160,8320,12480}  (4x 64x65 float2)
    __shared__ __align__(16) float2 F[16640];
    __shared__ float2 tw[128];
    float2* G2a = F;
    float2* G2b = F + 4160;
    float2* G2c = F + 8320;
    float2* G2d = F + 12480;
    int tid = threadIdx.x;
    int x = blockIdx.x;
    int b = x & 63, l1 = x >> 6;                       // j1 == 0
    const float2* ih = ihat + (size_t)b * NPIX;
    const float*  p1 = psi + (size_t)l1 * NPIX;
    buildTw(tw, tid);

    const float S1_128 = 9.3132257461547852e-10f;   // 2^-30
    const float S2TR   = 5.6843418860808015e-14f;   // 2^-44

    int kalo = tid >> 7, c = tid & 127;
    {
        #pragma unroll
        for (int i = 0; i < 2; ++i) {
            int ka = kalo + 4 * i;
            float2 g[16];
            #pragma unroll
            for (int kb = 0; kb < 16; ++kb) {
                int e = (16 * ka + kb) * NN + c;
                float2 z = ih[e];
                float  p = p1[e];
                g[kb] = make_float2(z.x * p, z.y * p);
            }
            fft16<1>(g);
            #pragma unroll
            for (int t = 0; t < 16; ++t)
                F[(16 * ka + t) * SS + c] = cmul(g[t], tw[t * ka]);
        }
    }
    __syncthreads();
    invB<SS, 1>(F, tid);      __syncthreads();
    invA<1, SS>(F, tw, tid);  __syncthreads();
    float acc = 0.f;
    invBmag_fwdA_row(F, tw, tid, acc);
    float ws1 = waveReduceSum(acc);
    if ((tid & 63) == 0) atomicAdd(&coeffs[b * 11 + 1], ws1 * S1_128);
    __syncthreads();
    fwdB<1, SS>(F, tid);      __syncthreads();
    fwdA<SS, 1>(F, tw, tid);  __syncthreads();
    float2 uh[32];
    fwdB_col_capture(F, tid, uh);
    __syncthreads();   // capture done -> F reusable (grids alias it)

    int m = c & 15;
    bool colKeep = (m < 4) || (m >= 12);
    int pc64 = 8 * (c >> 4) + ((m < 4) ? m : (m - 8));
    int fc = (c >> 4) + 8 * (c & 15);

    // ===== R23: H write to GLOBAL (central +-32 of uh; R13-proven scatter) =====
    {
        float2* Hf = Hg + ((size_t)(b * 4 + l1)) * 4096;
        if (colKeep) {
            #pragma unroll
            for (int i = 0; i < 2; ++i) {
                int ka = kalo + 4 * i;
                #pragma unroll
                for (int kb = 0; kb < 16; ++kb) {
                    if (kb < 4 || kb >= 12) {
                        int pr64 = 8 * ka + ((kb < 4) ? kb : (kb - 8));
                        Hf[pr64 * 64 + pc64] = uh[i * 16 + kb];
                    }
                }
            }
        }
    }

    {
        // ===== (j1=0, j2=1): ONE pass, 4 off-center 64-windows (R14 mapping) =====
        const int ORW[4] = {21, 15, 0, -15};
        const int OCW[4] = { 0, 15, 21,  15};
        bool ckw[4]; int pcw[4];
        #pragma unroll
        for (int w = 0; w < 4; ++w) {
            int dc = (fc - OCW[w]) & 127;
            ckw[w] = (dc < 32) || (dc >= 96);
            int uc = (dc < 32) ? dc : (dc - 64);
            pcw[w] = 8 * (uc & 7) + (uc >> 3);
        }
        #pragma unroll
        for (int i = 0; i < 2; ++i) {
            int ka = kalo + 4 * i;
            #pragma unroll
            for (int kb = 0; kb < 16; ++kb) {
                int fr = ka + 8 * kb;
                float2 z = uh[i * 16 + kb];
                int e = (16 * ka + kb) * NN + c;
                #pragma unroll
                for (int w = 0; w < 4; ++w) {
                    if (ckw[w]) {
                        int dr = (fr - ORW[w]) & 127;
                        if (dr < 32 || dr >= 96) {
                            int ur = (dr < 32) ? dr : (dr - 64);
                            int pr = 8 * (ur & 7) + (ur >> 3);
                            float pv = psi[(size_t)(4 + w) * NPIX + e];
                            float2* G = (w == 0) ? G2a : (w == 1) ? G2b
                                       : (w == 2) ? G2c : G2d;
                            G[pr * SG + pcw[w]] = make_float2(z.x * pv, z.y * pv);
                        }
                    }
                }
            }
        }
        __syncthreads();
        {   // col stepA (4 grids, full width)
            int col = tid & 63, k8 = tid >> 6;
            float2 f0[8], f1[8], f2[8], f3[8];
            #pragma unroll
            for (int kb = 0; kb < 8; ++kb) {
                int o = (8 * k8 + kb) * SG + col;
                f0[kb] = G2a[o]; f1[kb] = G2b[o]; f2[kb] = G2c[o]; f3[kb] = G2d[o];
            }
            fft8<1>(f0); fft8<1>(f1); fft8<1>(f2); fft8<1>(f3);
            #pragma unroll
            for (int q = 0; q < 8; ++q) {
                float2 w = tw[2 * q * k8];
                int o = (8 * k8 + q) * SG + col;
                G2a[o] = cmul(f0[q], w); G2b[o] = cmul(f1[q], w);
                G2c[o] = cmul(f2[q], w); G2d[o] = cmul(f3[q], w);
            }
        }
        __syncthreads();
        {   // col stepB
            int col = tid & 63, q = tid >> 6;
            float2 f0[8], f1[8], f2[8], f3[8];
            #pragma unroll
            for (int k8 = 0; k8 < 8; ++k8) {
                int o = (8 * k8 + q) * SG + col;
                f0[k8] = G2a[o]; f1[k8] = G2b[o]; f2[k8] = G2c[o]; f3[k8] = G2d[o];
            }
            fft8<1>(f0); fft8<1>(f1); fft8<1>(f2); fft8<1>(f3);
            #pragma unroll
            for (int n1 = 0; n1 < 8; ++n1) {
                int o = (8 * n1 + q) * SG + col;
                G2a[o] = f0[n1]; G2b[o] = f1[n1]; G2c[o] = f2[n1]; G2d[o] = f3[n1];
            }
        }
        __syncthreads();
        {   // row stepA
            int row = tid & 63, k8 = tid >> 6;
            int base = row * SG + 8 * k8;
            float2 f0[8], f1[8], f2[8], f3[8];
            #pragma unroll
            for (int kb = 0; kb < 8; ++kb) {
                f0[kb] = G2a[base + kb]; f1[kb] = G2b[base + kb];
                f2[kb] = G2c[base + kb]; f3[kb] = G2d[base + kb];
            }
            fft8<1>(f0); fft8<1>(f1); fft8<1>(f2); fft8<1>(f3);
            #pragma unroll
            for (int q = 0; q < 8; ++q) {
                float2 w = tw[2 * q * k8];
                G2a[base + q] = cmul(f0[q], w); G2b[base + q] = cmul(f1[q], w);
                G2c[base + q] = cmul(f2[q], w); G2d[base + q] = cmul(f3[q], w);
            }
        }
        __syncthreads();
        float a2 = 0.f;
        {   // row stepB + mag (all 4 -> same coeff)
            int row = tid & 63, q = tid >> 6;
            int base = row * SG + q;
            float2 f0[8], f1[8], f2[8], f3[8];
            #pragma unroll
            for (int k8 = 0; k8 < 8; ++k8) {
                int o = base + 8 * k8;
                f0[k8] = G2a[o]; f1[k8] = G2b[o]; f2[k8] = G2c[o]; f3[k8] = G2d[o];
            }
            fft8<1>(f0); fft8<1>(f1); fft8<1>(f2); fft8<1>(f3);
            #pragma unroll
            for (int n1 = 0; n1 < 8; ++n1) {
                a2 += sqrtf(f0[n1].x * f0[n1].x + f0[n1].y * f0[n1].y);
                a2 += sqrtf(f1[n1].x * f1[n1].x + f1[n1].y * f1[n1].y);
                a2 += sqrtf(f2[n1].x * f2[n1].x + f2[n1].y * f2[n1].y);
                a2 += sqrtf(f3[n1].x * f3[n1].x + f3[n1].y * f3[n1].y);
            }
        }
        float ws2 = waveReduceSum(a2);
        if ((tid & 63) == 0) atomicAdd(&coeffs[b * 11 + 5 + 0], ws2 * S2TR);
    }
}

// ---------- K_scat_small (R23): j1 in {1,2,3} + combo03 -- 2 blocks/CU ----------
__global__ __attribute__((amdgpu_flat_work_group_size(TT, TT), amdgpu_waves_per_eu(4, 4)))
void k_scat_small(const float2* __restrict__ ihat,
                  const float* __restrict__ psi,
                  float* __restrict__ coeffs,
                  const float2* __restrict__ Hg) {
    // S: 8448 float2 = 67,584 B.
    __shared__ __align__(16) float2 S[8448];
    __shared__ float2 tw[128];
    float2* G2  = S;
    float2* G32 = S;
    float2* Qs0 = S;
    float2* Qs1 = S + 1056;
    float2* Qs2 = S + 2112;
    float2* Qs3 = S + 3168;
    float4* Psa = (float4*)(S + 4224);
    float4* Psb = (float4*)(S + 6336);
    int tid = threadIdx.x;
    int x = blockIdx.x;
    int b = x & 63, l1 = (x >> 6) & 3;
    int t0 = x >> 8;   // 0 -> j1=1 (heavy), 1 -> combo03 (R23), 2 -> j1=2, 3 -> j1=3
    const float2* ih = ihat + (size_t)b * NPIX;
    const float*  p1 = psi + (size_t)(((t0 == 0) ? 1 : ((t0 == 2) ? 2 : 3)) * 4 + l1) * NPIX;
    buildTw(tw, tid);

    const float S1_64 = 3.7252902984619141e-9f;    // 2^-28
    const float S1_32 = 1.4901161193847656e-8f;    // 2^-26
    const float S2_32 = 9.0949470177292824e-13f;   // 2^-40 (32-grid from V64)

    int kalo = tid >> 7, c = tid & 127;

    if (t0 == 1) {
        // ===== R23 combo03: (0,2)+(0,3) from global H, proven 32-grid combo =====
        const float S2_03 = 2.2737367544323206e-13f;   // 2^-42
        const float2* Hf = Hg + ((size_t)(b * 4 + l1)) * 4096;
        int m = c & 15;
        bool colKeep = (m < 4) || (m >= 12);
        int pc64 = 8 * (c >> 4) + ((m < 4) ? m : (m - 8));
        int fc = (c >> 4) + 8 * (c & 15);
        const int OR2[4] = {9, 6, 0, -6};
        const int OC2[4] = {0, 6, 9,  6};
        bool ckq[4]; int pcq[4];
        #pragma unroll
        for (int w = 0; w < 4; ++w) {
            int dc = (fc - OC2[w]) & 127;
            ckq[w] = (dc < 16) || (dc >= 112);
            int f32c = (dc < 16) ? dc : (dc - 96);
            pcq[w] = 4 * (f32c & 7) + (f32c >> 3);
        }
        bool ck32 = (m < 2) || (m >= 14);
        int pc32 = 4 * (c >> 4) + ((m < 2) ? m : (m - 12));
        const float* p20 = psi + (size_t)8 * NPIX;
        const float* p30 = psi + (size_t)12 * NPIX;
        if (colKeep) {
            #pragma unroll
            for (int i = 0; i < 2; ++i) {
                int ka = kalo + 4 * i;
                #pragma unroll
                for (int kb = 0; kb < 16; ++kb) {
                    if (kb < 4 || kb >= 12) {
                        int pr64 = 8 * ka + ((kb < 4) ? kb : (kb - 8));
                        float2 z = Hf[pr64 * 64 + pc64];
                        int fr = ka + 8 * kb;
                        int e = (16 * ka + kb) * NN + c;
                        #pragma unroll
                        for (int w = 0; w < 4; ++w) {
                            if (ckq[w]) {
                                int dr = (fr - OR2[w]) & 127;
                                if (dr < 16 || dr >= 112) {
                                    int f32r = (dr < 16) ? dr : (dr - 96);
                                    int pr = 4 * (f32r & 7) + (f32r >> 3);
                                    float pv = p20[(size_t)w * NPIX + e];
                                    float2* Q = (w == 0) ? Qs0 : (w == 1) ? Qs1
                                               : (w == 2) ? Qs2 : Qs3;
                                    Q[pr * SG32 + pcq[w]] = make_float2(z.x * pv, z.y * pv);
                                }
                            }
                        }
                        if (ck32 && (kb < 2 || kb >= 14)) {
                            int pr32 = 4 * ka + ((kb < 2) ? kb : (kb - 12));
                            float a0 = p30[e], a1 = p30[NPIX + e];
                            float a2f = p30[2 * NPIX + e], a3 = p30[3 * NPIX + e];
                            Psa[pr32 * SG32 + pc32] =
                                make_float4(z.x * a0, z.y * a0, z.x * a1, z.y * a1);
                            Psb[pr32 * SG32 + pc32] =
                                make_float4(z.x * a2f, z.y * a2f, z.x * a3, z.y * a3);
                        }
                    }
                }
            }
        }
        float aq, ap;
        pass32combo(Qs0, Qs1, Qs2, Qs3, Psa, Psb, tw, tid, aq, ap);
        float wsq = waveReduceSum(aq);
        float wsp = waveReduceSum(ap);
        if ((tid & 63) == 0) {
            atomicAdd(&coeffs[b * 11 + 5 + 1], wsq * S2_03);
            atomicAdd(&coeffs[b * 11 + 5 + 2], wsp * S2_03);
        }
        return;
    }

    if (t0 == 0) {
        // =========== j1 = 1 on off-center 64-window (R16) ===========
        const int OR1[4] = {21, 15, 0, -15};
        const int OC1[4] = { 0, 15, 21,  15};
        int fc = (c >> 4) + 8 * (c & 15);
        int dc = (fc - OC1[l1]) & 127;
        bool ck = (dc < 32) || (dc >= 96);
        int ucw = (dc < 32) ? dc : (dc - 64);
        int pcd = 8 * (ucw & 7) + (ucw >> 3);
        if (ck) {
            #pragma unroll
            for (int i = 0; i < 2; ++i) {
                int ka = kalo + 4 * i;
                #pragma unroll
                for (int kb = 0; kb < 16; ++kb) {
                    int fr = ka + 8 * kb;
                    int dr = (fr - OR1[l1]) & 127;
                    if (dr < 32 || dr >= 96) {
                        int ur = (dr < 32) ? dr : (dr - 64);
                        int pr = 8 * (ur & 7) + (ur >> 3);
                        int e = (16 * ka + kb) * NN + c;
                        float2 z = ih[e];
                        float  p = p1[e];
                        G2[pr * SG + pcd] = make_float2(z.x * p, z.y * p);
                    }
                }
            }
        }
        __syncthreads();
        {   // col stepA (inverse)
            int col = tid & 63, k8 = tid >> 6;
            float2 f[8];
            #pragma unroll
            for (int kb = 0; kb < 8; ++kb) f[kb] = G2[(8 * k8 + kb) * SG + col];
            fft8<1>(f);
            #pragma unroll
            for (int q = 0; q < 8; ++q)
                G2[(8 * k8 + q) * SG + col] = cmul(f[q], tw[2 * q * k8]);
        }
        __syncthreads();
        {   // col stepB
            int col = tid & 63, q = tid >> 6;
            float2 f[8];
            #pragma unroll
            for (int k8 = 0; k8 < 8; ++k8) f[k8] = G2[(8 * k8 + q) * SG + col];
            fft8<1>(f);
            #pragma unroll
            for (int n1 = 0; n1 < 8; ++n1) G2[(8 * n1 + q) * SG + col] = f[n1];
        }
        __syncthreads();
        {   // row stepA (inverse)
            int row = tid & 63, k8 = tid >> 6;
            float2* R = G2 + row * SG + 8 * k8;
            float2 f[8];
            #pragma unroll
            for (int kb = 0; kb < 8; ++kb) f[kb] = R[kb];
            fft8<1>(f);
            #pragma unroll
            for (int q = 0; q < 8; ++q) R[q] = cmul(f[q], tw[2 * q * k8]);
        }
        __syncthreads();
        float acc = 0.f;
        {   // FUSED64: row stepB inv -> |.| -> row stepA fwd
            int row = tid & 63, q = tid >> 6;
            float2* R = G2 + row * SG + q;
            float2 f[8];
            #pragma unroll
            for (int k8 = 0; k8 < 8; ++k8) f[k8] = R[8 * k8];
            fft8<1>(f);
            #pragma unroll
            for (int n1 = 0; n1 < 8; ++n1) {
                float mg = sqrtf(f[n1].x * f[n1].x + f[n1].y * f[n1].y);
                acc += mg;
                f[n1] = make_float2(mg, 0.f);
            }
            fft8<-1>(f);
            #pragma unroll
            for (int ka = 0; ka < 8; ++ka)
                R[8 * ka] = cmulc(f[ka], tw[2 * q * ka]);
        }
        float ws1 = waveReduceSum(acc);
        if ((tid & 63) == 0) atomicAdd(&coeffs[b * 11 + 2], ws1 * S1_64);
        __syncthreads();
        {   // row stepB (forward)
            int row2 = tid & 63, ka = tid >> 6;
            float2* R2 = G2 + row2 * SG + 8 * ka;
            float2 g[8];
            #pragma unroll
            for (int t = 0; t < 8; ++t) g[t] = R2[t];
            fft8<-1>(g);
            #pragma unroll
            for (int kb = 0; kb < 8; ++kb) R2[kb] = g[kb];
        }
        __syncthreads();
        {   // col stepA (forward)
            int col = tid & 63, t = tid >> 6;
            float2 g[8];
            #pragma unroll
            for (int n1 = 0; n1 < 8; ++n1) g[n1] = G2[(t + 8 * n1) * SG + col];
            fft8<-1>(g);
            #pragma unroll
            for (int ka = 0; ka < 8; ++ka)
                G2[(t + 8 * ka) * SG + col] = cmulc(g[ka], tw[2 * t * ka]);
        }
        __syncthreads();
        float2 vh[8];
        int c6 = tid & 63, ka8 = tid >> 6;
        {   // col stepB (forward) -> V = u1hat_64 captured to registers
            float2 g[8];
            #pragma unroll
            for (int t = 0; t < 8; ++t) g[t] = G2[(8 * ka8 + t) * SG + c6];
            fft8<-1>(g);
            #pragma unroll
            for (int kb = 0; kb < 8; ++kb) vh[kb] = g[kb];
        }
        __syncthreads();   // G2 reads done -> combo grids (aliases) safe to write

        // psi gather indices: 64-grid storage p <-> freq u = 8*(p&7)+(p>>3);
        // 128-freq f128 = u<32 ? u : u+64; storage s = 16*(f128&7)+(f128>>3)
        int uc64 = 8 * (c6 & 7) + (c6 >> 3);
        int fc128 = (uc64 < 32) ? uc64 : (uc64 + 64);
        int scI = 16 * (fc128 & 7) + (fc128 >> 3);
        int se[8];
        #pragma unroll
        for (int kb = 0; kb < 8; ++kb) {
            int ur = 8 * kb + ka8;
            int fr128 = (ur < 32) ? ur : (ur + 64);
            se[kb] = (16 * (fr128 & 7) + (fr128 >> 3)) * NN + scI;
        }

        {   // ===== (1,2)+(1,3): fused 32-grid combo pass (R18) =====
            const int OR2[4] = {9, 6, 0, -6};
            const int OC2[4] = {0, 6, 9,  6};
            bool ckq[4]; int pcq[4];
            #pragma unroll
            for (int w = 0; w < 4; ++w) {
                int dcw = (uc64 - OC2[w]) & 63;
                ckq[w] = (dcw < 16) || (dcw >= 48);
                int f32c = (dcw < 16) ? dcw : (dcw - 32);
                pcq[w] = 4 * (f32c & 7) + (f32c >> 3);
            }
            int m6 = c6 & 7;
            bool ckV = (m6 < 2) || (m6 >= 6);
            int p32c = 4 * (c6 >> 3) + ((m6 < 2) ? m6 : (m6 - 4));
            const float* p30 = psi + (size_t)12 * NPIX;
            #pragma unroll
            for (int kb = 0; kb < 8; ++kb) {
                int ur = 8 * kb + ka8;
                float2 z = vh[kb];
                int e = se[kb];
                #pragma unroll
                for (int w = 0; w < 4; ++w) {
                    if (ckq[w]) {
                        int dr = (ur - OR2[w]) & 63;
                        if (dr < 16 || dr >= 48) {
                            int f32r = (dr < 16) ? dr : (dr - 32);
                            int pr = 4 * (f32r & 7) + (f32r >> 3);
                            float pv = psi[(size_t)(8 + w) * NPIX + e];
                            float2* Q = (w == 0) ? Qs0 : (w == 1) ? Qs1
                                       : (w == 2) ? Qs2 : Qs3;
                            Q[pr * SG32 + pcq[w]] = make_float2(z.x * pv, z.y * pv);
                        }
                    }
                }
                if (ckV && (kb < 2 || kb >= 6)) {
                    int pr32 = 4 * ka8 + (kb & 3);
                    float a0 = p30[e], a1 = p30[NPIX + e];
                    float a2f = p30[2 * NPIX + e], a3 = p30[3 * NPIX + e];
                    Psa[pr32 * SG32 + p32c] =
                        make_float4(z.x * a0, z.y * a0, z.x * a1, z.y * a1);
                    Psb[pr32 * SG32 + p32c] =
                        make_float4(z.x * a2f, z.y * a2f, z.x * a3, z.y * a3);
                }
            }
            float aq, ap;
            pass32combo(Qs0, Qs1, Qs2, Qs3, Psa, Psb, tw, tid, aq, ap);
            float wsq = waveReduceSum(aq);
            float wsp = waveReduceSum(ap);
            if ((tid & 63) == 0) {
                atomicAdd(&coeffs[b * 11 + 5 + 3], wsq * S2_32);
                atomicAdd(&coeffs[b * 11 + 5 + 4], wsp * S2_32);
            }
        }
        return;
    }

    if (t0 == 3) {
        // ===== j1=3: 32-grid first order (psi_{j1=3} support +-16) =====
        int m = c & 15;
        bool ck32 = (m < 2) || (m >= 14);
        int pc32 = 4 * (c >> 4) + ((m < 2) ? m : (m - 12));
        if (ck32) {
            #pragma unroll
            for (int i = 0; i < 2; ++i) {
                int ka = kalo + 4 * i;
                #pragma unroll
                for (int kb = 0; kb < 16; ++kb) {
                    if (kb < 2 || kb >= 14) {
                        int e = (16 * ka + kb) * NN + c;
                        float2 z = ih[e];
                        float  p = p1[e];
                        int pr32 = 4 * ka + ((kb < 2) ? kb : (kb - 12));
                        G32[pr32 * SG32 + pc32] = make_float2(z.x * p, z.y * p);
                    }
                }
            }
        }
        __syncthreads();
        if (tid < 256) {   // col stepA: fft4 over b per a (32 lines x 8 a)
            int line = tid & 31, a = tid >> 5;
            float2 f[4];
            #pragma unroll
            for (int kb = 0; kb < 4; ++kb) f[kb] = G32[(4 * a + kb) * SG32 + line];
            fft4<1>(f);
            #pragma unroll
            for (int t = 0; t < 4; ++t)
                G32[(4 * a + t) * SG32 + line] = cmul(f[t], tw[4 * t * a]);
        }
        __syncthreads();
        if (tid < 128) {   // col stepB: fft8 over a per t (32 lines x 4 t)
            int line = tid & 31, t = tid >> 5;
            float2 f[8];
            #pragma unroll
            for (int a = 0; a < 8; ++a) f[a] = G32[(4 * a + t) * SG32 + line];
            fft8<1>(f);
            #pragma unroll
            for (int n1 = 0; n1 < 8; ++n1) G32[(4 * n1 + t) * SG32 + line] = f[n1];
        }
        __syncthreads();
        if (tid < 256) {   // row stepA
            int row = tid & 31, a = tid >> 5;
            float2* R = G32 + row * SG32 + 4 * a;
            float2 f[4];
            #pragma unroll
            for (int kb = 0; kb < 4; ++kb) f[kb] = R[kb];
            fft4<1>(f);
            #pragma unroll
            for (int t = 0; t < 4; ++t) R[t] = cmul(f[t], tw[4 * t * a]);
        }
        __syncthreads();
        float acc = 0.f;
        if (tid < 128) {   // row stepB + mag
            int row = tid & 31, t = tid >> 5;
            float2* R = G32 + row * SG32 + t;
            float2 f[8];
            #pragma unroll
            for (int a = 0; a < 8; ++a) f[a] = R[4 * a];
            fft8<1>(f);
            #pragma unroll
            for (int n1 = 0; n1 < 8; ++n1)
                acc += sqrtf(f[n1].x * f[n1].x + f[n1].y * f[n1].y);
        }
        float ws1 = waveReduceSum(acc);
        if ((tid & 63) == 0 && tid < 128) atomicAdd(&coeffs[b * 11 + 4], ws1 * S1_32);
        return;
    }

    // ===== j1 == 2 (R20): ENTIRE branch on off-center 32-windows =====
    {
        const float S2_23 = 3.6379788070917130e-12f;   // 2^-38
        const int OR1[4] = {9, 6, 0, -6};
        const int OC1[4] = {0, 6, 9,  6};
        float2* G = S;                                  // 32x33 float2
        float4* Pa = (float4*)(S + 1088);               // S[1088..3200)
        float4* Pb = (float4*)(S + 3200);               // S[3200..5312)
        int fc = (c >> 4) + 8 * (c & 15);
        int dc = (fc - OC1[l1]) & 127;
        bool ck = (dc < 16) || (dc >= 112);
        int f32c = (dc < 16) ? dc : (dc - 96);
        int pcd = 4 * (f32c & 7) + (f32c >> 3);
        if (ck) {
            #pragma unroll
            for (int i = 0; i < 2; ++i) {
                int ka = kalo + 4 * i;
                #pragma unroll
                for (int kb = 0; kb < 16; ++kb) {
                    int fr = ka + 8 * kb;
                    int dr = (fr - OR1[l1]) & 127;
                    if (dr < 16 || dr >= 112) {
                        int f32r = (dr < 16) ? dr : (dr - 96);
                        int pr = 4 * (f32r & 7) + (f32r >> 3);
                        int e = (16 * ka + kb) * NN + c;
                        float2 z = ih[e];
                        float  p = p1[e];
                        G[pr * SG32 + pcd] = make_float2(z.x * p, z.y * p);
                    }
                }
            }
        }
        __syncthreads();
        if (tid < 256) {   // col stepA (inverse)
            int line = tid & 31, a = tid >> 5;
            float2 f[4];
            #pragma unroll
            for (int kb = 0; kb < 4; ++kb) f[kb] = G[(4 * a + kb) * SG32 + line];
            fft4<1>(f);
            #pragma unroll
            for (int t = 0; t < 4; ++t)
                G[(4 * a + t) * SG32 + line] = cmul(f[t], tw[4 * t * a]);
        }
        __syncthreads();
        if (tid < 128) {   // col stepB (inverse)
            int line = tid & 31, t = tid >> 5;
            float2 f[8];
            #pragma unroll
            for (int a = 0; a < 8; ++a) f[a] = G[(4 * a + t) * SG32 + line];
            fft8<1>(f);
            #pragma unroll
            for (int n1 = 0; n1 < 8; ++n1) G[(4 * n1 + t) * SG32 + line] = f[n1];
        }
        __syncthreads();
        if (tid < 256) {   // row stepA (inverse)
            int row = tid & 31, a = tid >> 5;
            float2* R = G + row * SG32 + 4 * a;
            float2 f[4];
            #pragma unroll
            for (int kb = 0; kb < 4; ++kb) f[kb] = R[kb];
            fft4<1>(f);
            #pragma unroll
            for (int t = 0; t < 4; ++t) R[t] = cmul(f[t], tw[4 * t * a]);
        }
        __syncthreads();
        float acc = 0.f;
        if (tid < 128) {   // row stepB (inverse) + mag + writeback (m,0)
            int row = tid & 31, t = tid >> 5;
            float2* R = G + row * SG32 + t;
            float2 f[8];
            #pragma unroll
            for (int a = 0; a < 8; ++a) f[a] = R[4 * a];
            fft8<1>(f);
            #pragma unroll
            for (int n1 = 0; n1 < 8; ++n1) {
                float mg = sqrtf(f[n1].x * f[n1].x + f[n1].y * f[n1].y);
                acc += mg;
                R[4 * n1] = make_float2(mg, 0.f);
            }
        }
        float ws1 = waveReduceSum(acc);
        if ((tid & 63) == 0 && tid < 128) atomicAdd(&coeffs[b * 11 + 3], ws1 * S1_32);
        __syncthreads();
        if (tid < 256) {   // row stepA (forward)
            int row = tid & 31, a = tid >> 5;
            float2* R = G + row * SG32 + 4 * a;
            float2 f[4];
            #pragma unroll
            for (int kb = 0; kb < 4; ++kb) f[kb] = R[kb];
            fft4<-1>(f);
            #pragma unroll
            for (int t = 0; t < 4; ++t) R[t] = cmulc(f[t], tw[4 * t * a]);
        }
        __syncthreads();
        if (tid < 128) {   // row stepB (forward)
            int row = tid & 31, t = tid >> 5;
            float2* R = G + row * SG32 + t;
            float2 f[8];
            #pragma unroll
            for (int a = 0; a < 8; ++a) f[a] = R[4 * a];
            fft8<-1>(f);
            #pragma unroll
            for (int n1 = 0; n1 < 8; ++n1) R[4 * n1] = f[n1];
        }
        __syncthreads();
        if (tid < 256) {   // col stepA (forward)
            int line = tid & 31, a = tid >> 5;
            float2 f[4];
            #pragma unroll
            for (int kb = 0; kb < 4; ++kb) f[kb] = G[(4 * a + kb) * SG32 + line];
            fft4<-1>(f);
            #pragma unroll
            for (int t = 0; t < 4; ++t)
                G[(4 * a + t) * SG32 + line] = cmulc(f[t], tw[4 * t * a]);
        }
        __syncthreads();
        if (tid < 128) {   // col stepB (forward) -> V32 in G (perm layout)
            int line = tid & 31, t = tid >> 5;
            float2 f[8];
            #pragma unroll
            for (int a = 0; a < 8; ++a) f[a] = G[(4 * a + t) * SG32 + line];
            fft8<-1>(f);
            #pragma unroll
            for (int n1 = 0; n1 < 8; ++n1) G[(4 * n1 + t) * SG32 + line] = f[n1];
        }
        __syncthreads();
        {   // (2,3) staging: dest slot == V32 slot (same perm); psi at slot freq
            const float* q0 = psi + (size_t)12 * NPIX;
            const float* q1 = q0 + NPIX;
            const float* q2 = q1 + NPIX;
            const float* q3 = q2 + NPIX;
            #pragma unroll
            for (int ii = 0; ii < 2; ++ii) {
                int s = ii * 512 + tid;
                int pr = s >> 5, pc = s & 31;
                int ur = (pr >> 2) + 8 * (pr & 3);
                int uc = (pc >> 2) + 8 * (pc & 3);
                int fr = (ur < 16) ? ur : (ur + 96);
                int fcc = (uc < 16) ? uc : (uc + 96);
                int e = (16 * (fr & 7) + (fr >> 3)) * NN
                      + 16 * (fcc & 7) + (fcc >> 3);
                float2 z = G[pr * SG32 + pc];
                float a0 = q0[e], a1 = q1[e], a2f = q2[e], a3 = q3[e];
                Pa[pr * SG32 + pc] = make_float4(z.x * a0, z.y * a0, z.x * a1, z.y * a1);
                Pb[pr * SG32 + pc] = make_float4(z.x * a2f, z.y * a2f, z.x * a3, z.y * a3);
            }
        }
        float a2 = pass32x4(Pa, Pb, tw, tid);
        float ws2 = waveReduceSum(a2);
        if ((tid & 63) == 0) atomicAdd(&coeffs[b * 11 + 5 + 5], ws2 * S2_23);
    }
}

// ---------- K_mlp: tiny MLP head (separate launch -- R12 lesson) ----------
__global__ void k_mlp(const float* __restrict__ coeffs,
                      const float* __restrict__ w1, const float* __restrict__ b1,
                      const float* __restrict__ w2, const float* __restrict__ b2,
                      float* __restrict__ out) {
    int b = threadIdx.x;
    if (b >= 64) return;
    float c[11];
    #pragma unroll
    for (int i = 0; i < 11; ++i) c[i] = coeffs[b * 11 + i];
    float h[4];
    #pragma unroll
    for (int k = 0; k < 4; ++k) {
        float s = b1[k];
        #pragma unroll
        for (int i = 0; i < 11; ++i) s += w1[k * 11 + i] * c[i];
        h[k] = fmaxf(s, 0.f);
    }
    #pragma unroll
    for (int o = 0; o < 10; ++o) {
        float s = b2[o];
        #pragma unroll
        for (int k = 0; k < 4; ++k) s += w2[o * 4 + k] * h[k];
        out[b * 10 + o] = 1.f / (1.f + expf(-s));
    }
}

extern "C" void kernel_launch(void* const* d_in, const int* in_sizes, int n_in,
                              void* d_out, int out_size, void* d_ws, size_t ws_size,
                              hipStream_t stream) {
    const float* img = (const float*)d_in[0];
    const float* w1  = (const float*)d_in[1];
    const float* b1  = (const float*)d_in[2];
    const float* w2  = (const float*)d_in[3];
    const float* b2  = (const float*)d_in[4];
    float* out = (float*)d_out;

    float*  ws     = (float*)d_ws;
    float*  psi    = ws;                                   // 16*NPIX floats
    float2* ihat   = (float2*)(ws + 16 * NPIX);            // 64*NPIX float2
    float2* Hg     = ihat + (size_t)64 * NPIX;             // 256*4096 float2 (R23)
    float*  coeffs = ws + 16 * NPIX + 2 * 64 * NPIX + 2 * 256 * 4096;

    hipLaunchKernelGGL(k_pre1,       dim3(385),  dim3(TT), 0, stream, img, psi, ihat, coeffs);
    hipLaunchKernelGGL(k_pre2,       dim3(256),  dim3(TT), 0, stream, ihat, coeffs);
    hipLaunchKernelGGL(k_scat_big,   dim3(256),  dim3(TT), 0, stream, ihat, psi, coeffs, Hg);
    hipLaunchKernelGGL(k_scat_small, dim3(1024), dim3(TT), 0, stream, ihat, psi, coeffs, Hg);
    hipLaunchKernelGGL(k_mlp,        dim3(1),    dim3(64), 0, stream, coeffs, w1, b1, w2, b2, out);
}